// Round 10
// baseline (727.264 us; speedup 1.0000x reference)
//
#include <hip/hip_runtime.h>

typedef __attribute__((ext_vector_type(8))) short short8;
typedef __attribute__((ext_vector_type(4))) float f32x4;

#define T_TOK  131072
#define DMODEL 256
#define DHID   512
#define NEXP   8

// ---------------- ws layout (bytes) ----------------
// xb        : 0          size 67108864   (T*256 bf16)
// w1b       : 67108864   size 2097152
// w2b       : 69206016   size 2097152
// tok_list  : 71303168   size 4194304    (E*T int)
// wt_list   : 75497472   size 4194304    (E*T float)
// pack      : 79691776   size 524288     (T int)
// tkw       : 80216064   size 1048576    (T float2)
// part_cnt  : 81264640   size 65536      (2048*8 int)
// part_psum : 81526784   size 65536
// block_off : 81788928   size 65536
// cnt_total : 82051072   size 64         (int[16]: counts + bases)
// H         : 83886080   size 268566528  ((2T+128) x 512 bf16)

__device__ __forceinline__ unsigned short f2bf(float f) {
  unsigned int u = __float_as_uint(f);
  u = (u + 0x7FFFu + ((u >> 16) & 1u)) >> 16;
  return (unsigned short)u;
}

__device__ __forceinline__ void gload16(const void* g, void* l) {
  __builtin_amdgcn_global_load_lds(
      (const __attribute__((address_space(1))) void*)g,
      (__attribute__((address_space(3))) void*)l, 16, 0, 0);
}

// ---------------- weight fp32 -> bf16 ----------------
__global__ void k_wconv(const float* __restrict__ w1, const float* __restrict__ w2,
                        unsigned short* __restrict__ w1b, unsigned short* __restrict__ w2b) {
  int i = blockIdx.x * 256 + threadIdx.x;
  float4 a = ((const float4*)w1)[i];
  ushort4 ua; ua.x = f2bf(a.x); ua.y = f2bf(a.y); ua.z = f2bf(a.z); ua.w = f2bf(a.w);
  ((ushort4*)w1b)[i] = ua;
  float4 b = ((const float4*)w2)[i];
  ushort4 ub; ub.x = f2bf(b.x); ub.y = f2bf(b.y); ub.z = f2bf(b.z); ub.w = f2bf(b.w);
  ((ushort4*)w2b)[i] = ub;
}

// ---------------- router: fp64 logits (bit-identical math), 64 tok/block ----------------
__global__ __launch_bounds__(256) void k_router(
    const float* __restrict__ x, const float* __restrict__ gate,
    unsigned short* __restrict__ xb, int* __restrict__ pack, float2* __restrict__ tkw,
    int* __restrict__ part_cnt, float* __restrict__ part_psum) {
  __shared__ float g[NEXP][DMODEL];
  __shared__ int s_cnt[NEXP];
  __shared__ float s_ps[NEXP];
  int tid = threadIdx.x;
  for (int i = tid; i < NEXP * DMODEL; i += 256) g[i >> 8][i & 255] = gate[i];
  if (tid < NEXP) { s_cnt[tid] = 0; s_ps[tid] = 0.f; }
  __syncthreads();
  int lane = tid & 63, wv = tid >> 6;
  float psacc[NEXP] = {0.f,0.f,0.f,0.f,0.f,0.f,0.f,0.f};
  for (int k = 0; k < 16; ++k) {
    int t = (blockIdx.x << 6) + (wv << 4) + k;
    const float* xr = x + (size_t)t * DMODEL;
    float4 x4 = *(const float4*)(xr + 4 * lane);
    ushort4 u4;
    u4.x = f2bf(x4.x); u4.y = f2bf(x4.y); u4.z = f2bf(x4.z); u4.w = f2bf(x4.w);
    *(ushort4*)(xb + (size_t)t * DMODEL + 4 * lane) = u4;
    double l[NEXP];
#pragma unroll
    for (int e = 0; e < NEXP; ++e) {
      const float4 g4 = *(const float4*)&g[e][4 * lane];
      l[e] = (double)x4.x * (double)g4.x + (double)x4.y * (double)g4.y +
             (double)x4.z * (double)g4.z + (double)x4.w * (double)g4.w;
    }
#pragma unroll
    for (int e = 0; e < NEXP; ++e) {
#pragma unroll
      for (int d = 32; d; d >>= 1) l[e] += __shfl_xor(l[e], d);
    }
    int i1 = 0;
#pragma unroll
    for (int e = 1; e < NEXP; ++e) if (l[e] > l[i1]) i1 = e;
    int i2 = (i1 == 0) ? 1 : 0;
#pragma unroll
    for (int e = 0; e < NEXP; ++e) if (e != i1 && l[e] > l[i2]) i2 = e;
    double m = l[0];
#pragma unroll
    for (int e = 1; e < NEXP; ++e) m = (l[e] > m) ? l[e] : m;
    float pe[NEXP]; float s = 0.f;
#pragma unroll
    for (int e = 0; e < NEXP; ++e) { pe[e] = __expf((float)(l[e] - m)); s += pe[e]; }
    float inv = 1.f / s;
    float p1 = pe[i1] * inv, p2 = pe[i2] * inv;
    float wn = 1.f / (p1 + p2);
    if (lane == 0) {
      pack[t] = i1 | (i2 << 8);
      tkw[t] = make_float2(p1 * wn, p2 * wn);
      atomicAdd(&s_cnt[i1], 1); atomicAdd(&s_cnt[i2], 1);
#pragma unroll
      for (int e = 0; e < NEXP; ++e) psacc[e] += pe[e] * inv;
    }
  }
  if (lane == 0) {
#pragma unroll
    for (int e = 0; e < NEXP; ++e) atomicAdd(&s_ps[e], psacc[e]);
  }
  __syncthreads();
  if (tid < NEXP) {
    part_cnt[blockIdx.x * NEXP + tid] = s_cnt[tid];
    part_psum[blockIdx.x * NEXP + tid] = s_ps[tid];
  }
}

// ---------------- scan: offsets, totals, expert bases, aux loss ----------------
__global__ __launch_bounds__(512) void k_scan(
    const int* __restrict__ part_cnt, const float* __restrict__ part_psum,
    int* __restrict__ block_off, int* __restrict__ cnt_total, float* __restrict__ out) {
  __shared__ float s_ps[NEXP];
  __shared__ int s_ct[NEXP];
  int lane = threadIdx.x & 63, wv = threadIdx.x >> 6;
  int base = lane * 32;
  int lsum = 0; float ps = 0.f;
#pragma unroll 8
  for (int j = 0; j < 32; ++j) {
    lsum += part_cnt[(base + j) * NEXP + wv];
    ps += part_psum[(base + j) * NEXP + wv];
  }
  int incl = lsum;
#pragma unroll
  for (int d = 1; d < 64; d <<= 1) { int t = __shfl_up(incl, d); if (lane >= d) incl += t; }
  int run = incl - lsum;
#pragma unroll 8
  for (int j = 0; j < 32; ++j) {
    int v = part_cnt[(base + j) * NEXP + wv];
    block_off[(base + j) * NEXP + wv] = run;
    run += v;
  }
#pragma unroll
  for (int d = 32; d; d >>= 1) ps += __shfl_xor(ps, d);
  int total = __shfl(incl, 63);
  if (lane == 0) { cnt_total[wv] = total; s_ct[wv] = total; s_ps[wv] = ps; }
  __syncthreads();
  if (threadIdx.x == 0) {
    double aux = 0.0; int rb = 0;
    for (int e = 0; e < NEXP; ++e) {
      aux += ((double)s_ct[e] / 131072.0) * ((double)s_ps[e] / 131072.0);
      cnt_total[8 + e] = rb; rb += s_ct[e];
    }
    out[33554432] = (float)(8.0 * aux);
  }
}

// ---------------- scatter (matches router's 64-token blocking) ----------------
__global__ void k_scatter(const int* __restrict__ pack, const float2* __restrict__ tkw,
                          const int* __restrict__ block_off, int* __restrict__ tok_list,
                          float* __restrict__ wt_list) {
  __shared__ int s_loc[NEXP];
  int tid = threadIdx.x;
  if (tid < NEXP) s_loc[tid] = 0;
  __syncthreads();
  int t = (blockIdx.x << 6) + tid;
  int p = pack[t];
  float2 wv = tkw[t];
  int e1 = p & 255, e2 = (p >> 8) & 255;
  int o1 = block_off[blockIdx.x * NEXP + e1];
  int p1 = atomicAdd(&s_loc[e1], 1);
  tok_list[e1 * T_TOK + o1 + p1] = t;
  wt_list[e1 * T_TOK + o1 + p1] = wv.x;
  int o2 = block_off[blockIdx.x * NEXP + e2];
  int p2 = atomicAdd(&s_loc[e2], 1);
  tok_list[e2 * T_TOK + o2 + p2] = t;
  wt_list[e2 * T_TOK + o2 + p2] = wv.y;
}

// ---------------- grouped GEMM1 + silu: H = silu(X @ W1^T + b1) ----------------
// 256x256 tile (ni = hid-half), K=256, BK=32 -> 8 steps. Tri-buffer (96KB),
// depth-2 prefetch, counted vmcnt(4): loads NEVER drain to 0 in the main loop
// -> continuous HBM streaming (fixes the R9 drain-phase-lock). Swizzle
// c ^ ((r>>1)&3) (2-way, free). 512 thr, 8 waves (2M x 4N), per-wave 128x64.
__global__ __launch_bounds__(512, 2) void k_gemm1(
    const unsigned short* __restrict__ xb, const unsigned short* __restrict__ w1b,
    const float* __restrict__ b1, const int* __restrict__ tok_list,
    const int* __restrict__ cnt_total, unsigned short* __restrict__ H) {
  __shared__ __align__(16) unsigned short buf[49152];  // A: 3x8192 u16, B: 3x8192 u16
  __shared__ int s_tok[256];

  int bid = (blockIdx.x & 7) * 258 + (blockIdx.x >> 3);
  int e = -1, loc = 0, cum = 0, cnte = 0;
#pragma unroll
  for (int ee = 0; ee < NEXP; ++ee) {
    int ct = cnt_total[ee];
    int nb = ((ct + 255) >> 8) * 2;
    if (e < 0 && bid < cum + nb) { e = ee; loc = bid - cum; cnte = ct; }
    cum += nb;
  }
  if (e < 0) return;
  int mi = loc >> 1, ni = loc & 1;
  int nv = cnte - (mi << 8); if (nv > 256) nv = 256;

  int tid = threadIdx.x;
  int lane = tid & 63, w = tid >> 6, l15 = lane & 15, lg = lane >> 4;
  int wr = w >> 2, wc = w & 3;

  float b1v[4];
#pragma unroll
  for (int nt = 0; nt < 4; ++nt)
    b1v[nt] = b1[e * DHID + ni * 256 + wc * 64 + nt * 16 + l15];

  if (tid < 256) s_tok[tid] = tok_list[e * T_TOK + (mi << 8) + (tid < nv ? tid : nv - 1)];
  __syncthreads();  // drains all VMEM (s_tok, b1v) -> clean vmcnt FIFO

  // staging map: slot s=j*512+tid -> row=j*128+(tid>>2), cslot=tid&3;
  // content chunk = cslot ^ ((row>>1)&3); (row>>1)&3 == (tid>>3)&3 (j-indep).
  int r0 = tid >> 2;
  int swz = (((tid & 3) ^ ((tid >> 3) & 3)) << 3);
  const unsigned short* w1e = w1b + ((size_t)e * DHID + ni * 256) * DMODEL;
  const unsigned short* pa[2];
  const unsigned short* pb[2];
#pragma unroll
  for (int j = 0; j < 2; ++j) {
    pa[j] = xb + (size_t)s_tok[j * 128 + r0] * DMODEL + swz;
    pb[j] = w1e + (size_t)(j * 128 + r0) * DMODEL + swz;
  }

  auto stage = [&](int s) {
    int ab = (s % 3) * 8192, bb = 24576 + (s % 3) * 8192;
#pragma unroll
    for (int j = 0; j < 2; ++j)
      gload16(pa[j] + s * 32, &buf[ab + (j * 512 + w * 64) * 8]);
#pragma unroll
    for (int j = 0; j < 2; ++j)
      gload16(pb[j] + s * 32, &buf[bb + (j * 512 + w * 64) * 8]);
  };

  f32x4 acc[8][4];
#pragma unroll
  for (int mt = 0; mt < 8; ++mt)
#pragma unroll
    for (int nt = 0; nt < 4; ++nt) acc[mt][nt] = (f32x4){0.f, 0.f, 0.f, 0.f};

  // prologue: FIFO=[s0(4), s1(4)]; vmcnt(4) drains s0, keeps s1 in flight
  stage(0); stage(1);
  asm volatile("s_waitcnt vmcnt(4)" ::: "memory");
  __builtin_amdgcn_s_barrier();
  __builtin_amdgcn_sched_barrier(0);

#pragma unroll
  for (int s = 0; s < 8; ++s) {
    if (s < 6) stage(s + 2);
    int ab = (s % 3) * 8192, bb = 24576 + (s % 3) * 8192;
    short8 a[8], b[4];
#pragma unroll
    for (int mt = 0; mt < 8; ++mt) {
      int r = wr * 128 + mt * 16 + l15;
      a[mt] = *(const short8*)&buf[ab + (r * 4 + (lg ^ ((r >> 1) & 3))) * 8];
    }
#pragma unroll
    for (int nt = 0; nt < 4; ++nt) {
      int r = wc * 64 + nt * 16 + l15;
      b[nt] = *(const short8*)&buf[bb + (r * 4 + (lg ^ ((r >> 1) & 3))) * 8];
    }
#pragma unroll
    for (int mt = 0; mt < 8; ++mt)
#pragma unroll
      for (int nt = 0; nt < 4; ++nt)
        acc[mt][nt] = __builtin_amdgcn_mfma_f32_16x16x32_bf16(a[mt], b[nt], acc[mt][nt], 0, 0, 0);
    if (s < 6) { asm volatile("s_waitcnt vmcnt(4)" ::: "memory"); }
    else       { asm volatile("s_waitcnt vmcnt(0)" ::: "memory"); }
    __builtin_amdgcn_s_barrier();
    __builtin_amdgcn_sched_barrier(0);
  }

  // epilogue: two 128-row half-bounces through buf (96KB > 64KB needed per half)
  int hb = cnt_total[8 + e];
#pragma unroll
  for (int h = 0; h < 2; ++h) {
    __syncthreads();
    if (wr == h) {
#pragma unroll
      for (int mt = 0; mt < 8; ++mt)
#pragma unroll
        for (int nt = 0; nt < 4; ++nt)
#pragma unroll
          for (int rr = 0; rr < 4; ++rr) {
            int lr = mt * 16 + lg * 4 + rr;          // local row 0..127
            int col = wc * 64 + nt * 16 + l15;
            float z = acc[mt][nt][rr] + b1v[nt];
            float sv = z / (1.f + __expf(-z));
            buf[lr * 256 + ((((col >> 3) ^ (lr & 7))) << 3) + (col & 7)] = f2bf(sv);
          }
    }
    __syncthreads();
#pragma unroll
    for (int i = 0; i < 8; ++i) {
      int t = i * 512 + tid;
      int lr = t >> 5, ch = t & 31;
      int grow = h * 128 + lr;
      if (grow < nv) {
        short8 v = *(const short8*)&buf[lr * 256 + (((ch ^ (lr & 7))) << 3)];
        *(short8*)&H[(size_t)(hb + (mi << 8) + grow) * DHID + ni * 256 + (ch << 3)] = v;
      }
    }
  }
}

// ---------------- grouped GEMM2 + scale + scatter: out += w*(H @ W2^T + b2) ----------------
// 256x256 tile (N = full DMODEL), K=512, BK=32 -> 16 steps. Same tri-buffer
// counted-vmcnt pipeline. A-rows clamped to nv-1 at expert tails.
__global__ __launch_bounds__(512, 2) void k_gemm2(
    const unsigned short* __restrict__ H, const unsigned short* __restrict__ w2b,
    const float* __restrict__ b2, const int* __restrict__ tok_list,
    const float* __restrict__ wt_list, const int* __restrict__ cnt_total,
    float* __restrict__ out) {
  __shared__ __align__(16) unsigned short buf[49152];
  __shared__ int s_tok[256];
  __shared__ float s_wt[256];

  int bid = (blockIdx.x & 7) * 129 + (blockIdx.x >> 3);
  int e = -1, mi = 0, cum = 0, cnte = 0;
#pragma unroll
  for (int ee = 0; ee < NEXP; ++ee) {
    int ct = cnt_total[ee];
    int nb = (ct + 255) >> 8;
    if (e < 0 && bid < cum + nb) { e = ee; mi = bid - cum; cnte = ct; }
    cum += nb;
  }
  if (e < 0) return;
  int nv = cnte - (mi << 8); if (nv > 256) nv = 256;

  int tid = threadIdx.x;
  int lane = tid & 63, w = tid >> 6, l15 = lane & 15, lg = lane >> 4;
  int wr = w >> 2, wc = w & 3;

  float b2v[4];
#pragma unroll
  for (int nt = 0; nt < 4; ++nt)
    b2v[nt] = b2[e * DMODEL + wc * 64 + nt * 16 + l15];

  if (tid < 256) {
    int idx = e * T_TOK + (mi << 8) + (tid < nv ? tid : nv - 1);
    s_tok[tid] = tok_list[idx];
    s_wt[tid] = (tid < nv) ? wt_list[idx] : 0.f;
  }
  __syncthreads();

  int hb = cnt_total[8 + e];
  const unsigned short* hrows = H + (size_t)(hb + (mi << 8)) * DHID;
  const unsigned short* w2e = w2b + (size_t)e * DMODEL * DHID;

  int r0 = tid >> 2;
  int swz = (((tid & 3) ^ ((tid >> 3) & 3)) << 3);
  const unsigned short* pa[2];
  const unsigned short* pb[2];
#pragma unroll
  for (int j = 0; j < 2; ++j) {
    int r = j * 128 + r0;
    int rc = (r < nv) ? r : (nv - 1);
    pa[j] = hrows + (size_t)rc * DHID + swz;
    pb[j] = w2e + (size_t)(j * 128 + r0) * DHID + swz;
  }

  auto stage = [&](int s) {
    int ab = (s % 3) * 8192, bb = 24576 + (s % 3) * 8192;
#pragma unroll
    for (int j = 0; j < 2; ++j)
      gload16(pa[j] + s * 32, &buf[ab + (j * 512 + w * 64) * 8]);
#pragma unroll
    for (int j = 0; j < 2; ++j)
      gload16(pb[j] + s * 32, &buf[bb + (j * 512 + w * 64) * 8]);
  };

  f32x4 acc[8][4];
#pragma unroll
  for (int mt = 0; mt < 8; ++mt)
#pragma unroll
    for (int nt = 0; nt < 4; ++nt) acc[mt][nt] = (f32x4){0.f, 0.f, 0.f, 0.f};

  stage(0); stage(1);
  asm volatile("s_waitcnt vmcnt(4)" ::: "memory");
  __builtin_amdgcn_s_barrier();
  __builtin_amdgcn_sched_barrier(0);

#pragma unroll
  for (int s = 0; s < 16; ++s) {
    if (s < 14) stage(s + 2);
    int ab = (s % 3) * 8192, bb = 24576 + (s % 3) * 8192;
    short8 a[8], b[4];
#pragma unroll
    for (int mt = 0; mt < 8; ++mt) {
      int r = wr * 128 + mt * 16 + l15;
      a[mt] = *(const short8*)&buf[ab + (r * 4 + (lg ^ ((r >> 1) & 3))) * 8];
    }
#pragma unroll
    for (int nt = 0; nt < 4; ++nt) {
      int r = wc * 64 + nt * 16 + l15;
      b[nt] = *(const short8*)&buf[bb + (r * 4 + (lg ^ ((r >> 1) & 3))) * 8];
    }
#pragma unroll
    for (int mt = 0; mt < 8; ++mt)
#pragma unroll
      for (int nt = 0; nt < 4; ++nt)
        acc[mt][nt] = __builtin_amdgcn_mfma_f32_16x16x32_bf16(a[mt], b[nt], acc[mt][nt], 0, 0, 0);
    if (s < 14) { asm volatile("s_waitcnt vmcnt(4)" ::: "memory"); }
    else        { asm volatile("s_waitcnt vmcnt(0)" ::: "memory"); }
    __builtin_amdgcn_s_barrier();
    __builtin_amdgcn_sched_barrier(0);
  }

  // epilogue: out[tok, col] += wt * (acc + b2[col])
#pragma unroll
  for (int mt = 0; mt < 8; ++mt)
#pragma unroll
    for (int rr = 0; rr < 4; ++rr) {
      int row = wr * 128 + mt * 16 + lg * 4 + rr;
      if (row < nv) {
        float wt = s_wt[row];
        float* orow = out + (size_t)s_tok[row] * DMODEL;
#pragma unroll
        for (int nt = 0; nt < 4; ++nt)
          atomicAdd(orow + wc * 64 + nt * 16 + l15, wt * (acc[mt][nt][rr] + b2v[nt]));
      }
    }
}

extern "C" void kernel_launch(void* const* d_in, const int* in_sizes, int n_in,
                              void* d_out, int out_size, void* d_ws, size_t ws_size,
                              hipStream_t stream) {
  const float* x    = (const float*)d_in[0];
  const float* gate = (const float*)d_in[1];
  const float* w1   = (const float*)d_in[2];
  const float* b1   = (const float*)d_in[3];
  const float* w2   = (const float*)d_in[4];
  const float* b2   = (const float*)d_in[5];
  float* out = (float*)d_out;
  char* ws = (char*)d_ws;

  unsigned short* xb  = (unsigned short*)(ws);
  unsigned short* w1b = (unsigned short*)(ws + 67108864);
  unsigned short* w2b = (unsigned short*)(ws + 69206016);
  int*    tok_list  = (int*)(ws + 71303168);
  float*  wt_list   = (float*)(ws + 75497472);
  int*    pack      = (int*)(ws + 79691776);
  float2* tkw       = (float2*)(ws + 80216064);
  int*    part_cnt  = (int*)(ws + 81264640);
  float*  part_psum = (float*)(ws + 81526784);
  int*    block_off = (int*)(ws + 81788928);
  int*    cnt_total = (int*)(ws + 82051072);
  unsigned short* H = (unsigned short*)(ws + 83886080);

  hipMemsetAsync(d_out, 0, (size_t)out_size * 4, stream);
  k_wconv<<<1024, 256, 0, stream>>>(w1, w2, w1b, w2b);
  k_router<<<2048, 256, 0, stream>>>(x, gate, xb, pack, tkw, part_cnt, part_psum);
  k_scan<<<1, 512, 0, stream>>>(part_cnt, part_psum, block_off, cnt_total, out);
  k_scatter<<<2048, 64, 0, stream>>>(pack, tkw, block_off, tok_list, wt_list);
  k_gemm1<<<2064, 512, 0, stream>>>(xb, w1b, b1, tok_list, cnt_total, H);
  k_gemm2<<<1032, 512, 0, stream>>>(H, w2b, b2, tok_list, wt_list, cnt_total, out);
}

// Round 12
// 707.089 us; speedup vs baseline: 1.0285x; 1.0285x over previous
//
#include <hip/hip_runtime.h>

typedef __attribute__((ext_vector_type(8))) short short8;
typedef __attribute__((ext_vector_type(4))) float f32x4;

#define T_TOK  131072
#define DMODEL 256
#define DHID   512
#define NEXP   8

// ---------------- ws layout (bytes) ----------------
// xb        : 0          size 67108864   (T*256 bf16)
// P1        : 67108864   size 2097152    W1 panels [e][kc4][512][64] pre-swizzled
// P2        : 69206016   size 2097152    W2 panels [e][kc8][256][64] pre-swizzled
// tok_list  : 71303168   size 1064960    (padded-base layout)
// wt_list   : 72368128   size 1064960
// pack      : 73433088   size 524288
// tkw       : 73957376   size 1048576
// part_cnt  : 75005952   size 65536
// part_psum : 75071488   size 65536
// block_off : 75137024   size 65536
// cnt_total : 75202560   size 64         int[16]: counts + 256-PADDED bases
// Hp        : 75497472   size 270532608  H panels [blk][kc8][256][64] pre-swizzled

__device__ __forceinline__ unsigned short f2bf(float f) {
  unsigned int u = __float_as_uint(f);
  u = (u + 0x7FFFu + ((u >> 16) & 1u)) >> 16;
  return (unsigned short)u;
}

__device__ __forceinline__ void gload16(const void* g, void* l) {
  __builtin_amdgcn_global_load_lds(
      (const __attribute__((address_space(1))) void*)g,
      (__attribute__((address_space(3))) void*)l, 16, 0, 0);
}

// ---------------- weight fp32 -> bf16 K-panels (pre-swizzled) ----------------
__global__ void k_wconv(const float* __restrict__ w1, const float* __restrict__ w2,
                        unsigned short* __restrict__ P1, unsigned short* __restrict__ P2) {
  int g = blockIdx.x * 256 + threadIdx.x;  // 131072 threads
  int e = g >> 14, rem = g & 16383;
  {
    int row = rem >> 5, c = rem & 31;      // 512 rows x 32 chunks (K=256)
    int kc = c >> 3, cs = c & 7;
    const float* s = w1 + ((size_t)e * DHID + row) * DMODEL + c * 8;
    short8 v;
#pragma unroll
    for (int j = 0; j < 8; ++j) v[j] = (short)f2bf(s[j]);
    size_t dc = ((size_t)(e * 4 + kc) * 512 + row) * 8 + (cs ^ (row & 7));
    *(short8*)(P1 + dc * 8) = v;
  }
  {
    int row = rem >> 6, c = rem & 63;      // 256 rows x 64 chunks (K=512)
    int kc = c >> 3, cs = c & 7;
    const float* s = w2 + ((size_t)e * DMODEL + row) * DHID + c * 8;
    short8 v;
#pragma unroll
    for (int j = 0; j < 8; ++j) v[j] = (short)f2bf(s[j]);
    size_t dc = ((size_t)(e * 8 + kc) * 256 + row) * 8 + (cs ^ (row & 7));
    *(short8*)(P2 + dc * 8) = v;
  }
}

// ---------------- router: fp64 logits (bit-identical math), 64 tok/block ----------------
__global__ __launch_bounds__(256) void k_router(
    const float* __restrict__ x, const float* __restrict__ gate,
    unsigned short* __restrict__ xb, int* __restrict__ pack, float2* __restrict__ tkw,
    int* __restrict__ part_cnt, float* __restrict__ part_psum) {
  __shared__ float g[NEXP][DMODEL];
  __shared__ int s_cnt[NEXP];
  __shared__ float s_ps[NEXP];
  int tid = threadIdx.x;
  for (int i = tid; i < NEXP * DMODEL; i += 256) g[i >> 8][i & 255] = gate[i];
  if (tid < NEXP) { s_cnt[tid] = 0; s_ps[tid] = 0.f; }
  __syncthreads();
  int lane = tid & 63, wv = tid >> 6;
  float psacc[NEXP] = {0.f,0.f,0.f,0.f,0.f,0.f,0.f,0.f};
  for (int k = 0; k < 16; ++k) {
    int t = (blockIdx.x << 6) + (wv << 4) + k;
    const float* xr = x + (size_t)t * DMODEL;
    float4 x4 = *(const float4*)(xr + 4 * lane);
    ushort4 u4;
    u4.x = f2bf(x4.x); u4.y = f2bf(x4.y); u4.z = f2bf(x4.z); u4.w = f2bf(x4.w);
    *(ushort4*)(xb + (size_t)t * DMODEL + 4 * lane) = u4;
    double l[NEXP];
#pragma unroll
    for (int e = 0; e < NEXP; ++e) {
      const float4 g4 = *(const float4*)&g[e][4 * lane];
      l[e] = (double)x4.x * (double)g4.x + (double)x4.y * (double)g4.y +
             (double)x4.z * (double)g4.z + (double)x4.w * (double)g4.w;
    }
#pragma unroll
    for (int e = 0; e < NEXP; ++e) {
#pragma unroll
      for (int d = 32; d; d >>= 1) l[e] += __shfl_xor(l[e], d);
    }
    int i1 = 0;
#pragma unroll
    for (int e = 1; e < NEXP; ++e) if (l[e] > l[i1]) i1 = e;
    int i2 = (i1 == 0) ? 1 : 0;
#pragma unroll
    for (int e = 0; e < NEXP; ++e) if (e != i1 && l[e] > l[i2]) i2 = e;
    double m = l[0];
#pragma unroll
    for (int e = 1; e < NEXP; ++e) m = (l[e] > m) ? l[e] : m;
    float pe[NEXP]; float s = 0.f;
#pragma unroll
    for (int e = 0; e < NEXP; ++e) { pe[e] = __expf((float)(l[e] - m)); s += pe[e]; }
    float inv = 1.f / s;
    float p1 = pe[i1] * inv, p2 = pe[i2] * inv;
    float wn = 1.f / (p1 + p2);
    if (lane == 0) {
      pack[t] = i1 | (i2 << 8);
      tkw[t] = make_float2(p1 * wn, p2 * wn);
      atomicAdd(&s_cnt[i1], 1); atomicAdd(&s_cnt[i2], 1);
#pragma unroll
      for (int e = 0; e < NEXP; ++e) psacc[e] += pe[e] * inv;
    }
  }
  if (lane == 0) {
#pragma unroll
    for (int e = 0; e < NEXP; ++e) atomicAdd(&s_ps[e], psacc[e]);
  }
  __syncthreads();
  if (tid < NEXP) {
    part_cnt[blockIdx.x * NEXP + tid] = s_cnt[tid];
    part_psum[blockIdx.x * NEXP + tid] = s_ps[tid];
  }
}

// ---------------- scan: offsets, totals, 256-PADDED expert bases, aux loss ----------------
__global__ __launch_bounds__(512) void k_scan(
    const int* __restrict__ part_cnt, const float* __restrict__ part_psum,
    int* __restrict__ block_off, int* __restrict__ cnt_total, float* __restrict__ out) {
  __shared__ float s_ps[NEXP];
  __shared__ int s_ct[NEXP];
  int lane = threadIdx.x & 63, wv = threadIdx.x >> 6;
  int base = lane * 32;
  int lsum = 0; float ps = 0.f;
#pragma unroll 8
  for (int j = 0; j < 32; ++j) {
    lsum += part_cnt[(base + j) * NEXP + wv];
    ps += part_psum[(base + j) * NEXP + wv];
  }
  int incl = lsum;
#pragma unroll
  for (int d = 1; d < 64; d <<= 1) { int t = __shfl_up(incl, d); if (lane >= d) incl += t; }
  int run = incl - lsum;
#pragma unroll 8
  for (int j = 0; j < 32; ++j) {
    int v = part_cnt[(base + j) * NEXP + wv];
    block_off[(base + j) * NEXP + wv] = run;
    run += v;
  }
#pragma unroll
  for (int d = 32; d; d >>= 1) ps += __shfl_xor(ps, d);
  int total = __shfl(incl, 63);
  if (lane == 0) { cnt_total[wv] = total; s_ct[wv] = total; s_ps[wv] = ps; }
  __syncthreads();
  if (threadIdx.x == 0) {
    double aux = 0.0; int rb = 0;
    for (int e = 0; e < NEXP; ++e) {
      aux += ((double)s_ct[e] / 131072.0) * ((double)s_ps[e] / 131072.0);
      cnt_total[8 + e] = rb;
      rb += (s_ct[e] + 255) & ~255;   // 256-aligned padded base
    }
    out[33554432] = (float)(8.0 * aux);
  }
}

// ---------------- scatter into padded-base per-expert lists ----------------
__global__ void k_scatter(const int* __restrict__ pack, const float2* __restrict__ tkw,
                          const int* __restrict__ block_off, const int* __restrict__ cnt_total,
                          int* __restrict__ tok_list, float* __restrict__ wt_list) {
  __shared__ int s_loc[NEXP];
  int tid = threadIdx.x;
  if (tid < NEXP) s_loc[tid] = 0;
  __syncthreads();
  int t = (blockIdx.x << 6) + tid;
  int p = pack[t];
  float2 wv = tkw[t];
  int e1 = p & 255, e2 = (p >> 8) & 255;
  int o1 = block_off[blockIdx.x * NEXP + e1];
  int p1 = atomicAdd(&s_loc[e1], 1);
  int i1 = cnt_total[8 + e1] + o1 + p1;
  tok_list[i1] = t; wt_list[i1] = wv.x;
  int o2 = block_off[blockIdx.x * NEXP + e2];
  int p2 = atomicAdd(&s_loc[e2], 1);
  int i2 = cnt_total[8 + e2] + o2 + p2;
  tok_list[i2] = t; wt_list[i2] = wv.y;
}

// ---------------- grouped GEMM1 + silu -> Hp panels ----------------
// M=128 tile, N=256 (ni half of DHID), K=256 staged FULLY for A. All gload16
// LDS dests are explicitly wave-uniform. Hp store guard is LOCAL row < nv
// (R11 BUG: used (mi<<7)+row < nv -> all mi>=1 tiles zeroed).
__global__ __launch_bounds__(512, 2) void k_gemm1(
    const unsigned short* __restrict__ xb, const unsigned short* __restrict__ P1,
    const float* __restrict__ b1, const int* __restrict__ tok_list,
    const int* __restrict__ cnt_total, unsigned short* __restrict__ Hp) {
  __shared__ __align__(16) unsigned short buf[65536];  // A:[0,32768) B0:[32768..) B1:[49152..)
  __shared__ int s_tok[128];

  int bid = (blockIdx.x & 7) * 514 + (blockIdx.x >> 3);  // grid 4112 = 8*514
  int e = -1, loc = 0, cum = 0, cnte = 0;
#pragma unroll
  for (int ee = 0; ee < NEXP; ++ee) {
    int ct = cnt_total[ee];
    int nb = ((ct + 127) >> 7) * 2;
    if (e < 0 && bid < cum + nb) { e = ee; loc = bid - cum; cnte = ct; }
    cum += nb;
  }
  if (e < 0) return;
  int mi = loc >> 1, ni = loc & 1;
  int nv = cnte - (mi << 7); if (nv > 128) nv = 128;
  int hbp = cnt_total[8 + e];

  int tid = threadIdx.x;
  int lane = tid & 63, w = tid >> 6, l15 = lane & 15, lg = lane >> 4;
  int wr = w >> 2, wc = w & 3;  // 2M x 4N waves, per-wave 64x64

  float b1v[4];
#pragma unroll
  for (int nt = 0; nt < 4; ++nt)
    b1v[nt] = b1[e * DHID + ni * 256 + wc * 64 + nt * 16 + l15];

  if (tid < 128) s_tok[tid] = tok_list[hbp + (mi << 7) + (tid < nv ? tid : nv - 1)];
  __syncthreads();

  // stage A: full K, 8 chunks/thread; per-lane swizzled source, uniform dest
#pragma unroll
  for (int i = 0; i < 8; ++i) {
    int cidx = i * 512 + tid;
    int row = cidx >> 5, c = cidx & 31;
    gload16(xb + (size_t)s_tok[row] * DMODEL + (size_t)((c ^ (row & 7)) << 3),
            &buf[(size_t)(i * 512 + w * 64) * 8]);
  }
  auto stage_b = [&](int kc) {
    const unsigned short* src = P1 + ((size_t)(e * 4 + kc) * 512 + ni * 256) * 64;
    int d = 32768 + (kc & 1) * 16384;
#pragma unroll
    for (int i = 0; i < 4; ++i) {
      int cidx = i * 512 + tid;
      gload16(src + (size_t)cidx * 8, &buf[d + (i * 512 + w * 64) * 8]);
    }
  };
  stage_b(0);
  asm volatile("s_waitcnt vmcnt(0)" ::: "memory");
  __builtin_amdgcn_s_barrier();
  __builtin_amdgcn_sched_barrier(0);

  f32x4 acc[4][4];
#pragma unroll
  for (int mt = 0; mt < 4; ++mt)
#pragma unroll
    for (int nt = 0; nt < 4; ++nt) acc[mt][nt] = (f32x4){0.f, 0.f, 0.f, 0.f};

  for (int s = 0; s < 4; ++s) {
    if (s < 3) stage_b(s + 1);
    int bb = 32768 + (s & 1) * 16384;
#pragma unroll
    for (int ks = 0; ks < 2; ++ks) {
      int q = ks * 4 + lg;
      short8 a[4], b[4];
#pragma unroll
      for (int mt = 0; mt < 4; ++mt) {
        int r = wr * 64 + mt * 16 + l15;
        int ch = s * 8 + q;
        a[mt] = *(const short8*)&buf[((size_t)r * 32 + (ch ^ (r & 7))) * 8];
      }
#pragma unroll
      for (int nt = 0; nt < 4; ++nt) {
        int r = wc * 64 + nt * 16 + l15;
        b[nt] = *(const short8*)&buf[bb + ((size_t)r * 8 + (q ^ (r & 7))) * 8];
      }
#pragma unroll
      for (int mt = 0; mt < 4; ++mt)
#pragma unroll
        for (int nt = 0; nt < 4; ++nt)
          acc[mt][nt] = __builtin_amdgcn_mfma_f32_16x16x32_bf16(a[mt], b[nt], acc[mt][nt], 0, 0, 0);
    }
    asm volatile("s_waitcnt vmcnt(0)" ::: "memory");
    __builtin_amdgcn_s_barrier();
    __builtin_amdgcn_sched_barrier(0);
  }

  // epilogue: silu -> LDS bounce (slot = (col>>3)^(row&7)) -> Hp panel store
#pragma unroll
  for (int mt = 0; mt < 4; ++mt)
#pragma unroll
    for (int nt = 0; nt < 4; ++nt)
#pragma unroll
      for (int rr = 0; rr < 4; ++rr) {
        int row = wr * 64 + mt * 16 + lg * 4 + rr;   // 0..127
        int col = wc * 64 + nt * 16 + l15;           // 0..255
        float z = acc[mt][nt][rr] + b1v[nt];
        float sv = z / (1.f + __expf(-z));
        buf[(size_t)row * 256 + (((col >> 3) ^ (row & 7)) << 3) + (col & 7)] = f2bf(sv);
      }
  __syncthreads();
  int blk = (hbp >> 8) + (mi >> 1);
  int rbase = (mi & 1) * 128;
#pragma unroll
  for (int i = 0; i < 8; ++i) {
    int cidx = i * 512 + tid;
    int row = cidx >> 5, s32 = cidx & 31;
    int c32 = s32 ^ (row & 7);                       // content chunk at raw slot s32
    int kc = ni * 4 + (c32 >> 3), cs = c32 & 7;
    short8 v;
    if (row < nv) v = *(const short8*)&buf[(size_t)row * 256 + s32 * 8];  // LOCAL row guard
    else { short8 z8 = {0,0,0,0,0,0,0,0}; v = z8; }
    size_t dc = ((size_t)(blk * 8 + kc) * 256 + rbase + row) * 8 + (cs ^ (row & 7));
    *(short8*)&Hp[dc * 8] = v;
  }
}

// ---------------- grouped GEMM2 + scale + scatter: out += w*(H @ W2^T + b2) ----------------
// 256x256 tile, K=512, BK=64, dbuf. A = Hp panels, B = P2 panels: ALL staging
// is pure linear 1KB-contiguous wave instructions with uniform LDS dests.
__global__ __launch_bounds__(512, 2) void k_gemm2(
    const unsigned short* __restrict__ Hp, const unsigned short* __restrict__ P2,
    const float* __restrict__ b2, const int* __restrict__ tok_list,
    const float* __restrict__ wt_list, const int* __restrict__ cnt_total,
    float* __restrict__ out) {
  __shared__ __align__(16) unsigned short buf[65536];  // [s&1]: A 16384 u16 + B 16384 u16
  __shared__ int s_tok[256];
  __shared__ float s_wt[256];

  int bid = (blockIdx.x & 7) * 129 + (blockIdx.x >> 3);  // grid 1032 = 8*129
  int e = -1, mi = 0, cum = 0, cnte = 0;
#pragma unroll
  for (int ee = 0; ee < NEXP; ++ee) {
    int ct = cnt_total[ee];
    int nb = (ct + 255) >> 8;
    if (e < 0 && bid < cum + nb) { e = ee; mi = bid - cum; cnte = ct; }
    cum += nb;
  }
  if (e < 0) return;
  int nv = cnte - (mi << 8); if (nv > 256) nv = 256;
  int hbp = cnt_total[8 + e];
  int blk = (hbp >> 8) + mi;

  int tid = threadIdx.x;
  int lane = tid & 63, w = tid >> 6, l15 = lane & 15, lg = lane >> 4;
  int wr = w >> 2, wc = w & 3;

  float b2v[4];
#pragma unroll
  for (int nt = 0; nt < 4; ++nt)
    b2v[nt] = b2[e * DMODEL + wc * 64 + nt * 16 + l15];

  if (tid < 256) {
    int idx = hbp + (mi << 8) + (tid < nv ? tid : nv - 1);
    s_tok[tid] = tok_list[idx];
    s_wt[tid] = (tid < nv) ? wt_list[idx] : 0.f;
  }
  __syncthreads();

  auto stage = [&](int s) {
    int d = (s & 1) * 32768;
    const unsigned short* sa = Hp + (size_t)(blk * 8 + s) * 16384;
    const unsigned short* sb = P2 + (size_t)(e * 8 + s) * 16384;
#pragma unroll
    for (int i = 0; i < 4; ++i) {
      int c = i * 512 + tid;
      gload16(sa + (size_t)c * 8, &buf[d + (i * 512 + w * 64) * 8]);
    }
#pragma unroll
    for (int i = 0; i < 4; ++i) {
      int c = i * 512 + tid;
      gload16(sb + (size_t)c * 8, &buf[d + 16384 + (i * 512 + w * 64) * 8]);
    }
  };

  f32x4 acc[8][4];
#pragma unroll
  for (int mt = 0; mt < 8; ++mt)
#pragma unroll
    for (int nt = 0; nt < 4; ++nt) acc[mt][nt] = (f32x4){0.f, 0.f, 0.f, 0.f};

  stage(0);
  asm volatile("s_waitcnt vmcnt(0)" ::: "memory");
  __builtin_amdgcn_s_barrier();
  __builtin_amdgcn_sched_barrier(0);

  for (int s = 0; s < 8; ++s) {
    if (s < 7) stage(s + 1);
    int ab = (s & 1) * 32768, bb = ab + 16384;
#pragma unroll
    for (int ks = 0; ks < 2; ++ks) {
      int q = ks * 4 + lg;
      short8 a[8], b[4];
#pragma unroll
      for (int mt = 0; mt < 8; ++mt) {
        int r = wr * 128 + mt * 16 + l15;
        a[mt] = *(const short8*)&buf[ab + ((size_t)r * 8 + (q ^ (r & 7))) * 8];
      }
#pragma unroll
      for (int nt = 0; nt < 4; ++nt) {
        int r = wc * 64 + nt * 16 + l15;
        b[nt] = *(const short8*)&buf[bb + ((size_t)r * 8 + (q ^ (r & 7))) * 8];
      }
#pragma unroll
      for (int mt = 0; mt < 8; ++mt)
#pragma unroll
        for (int nt = 0; nt < 4; ++nt)
          acc[mt][nt] = __builtin_amdgcn_mfma_f32_16x16x32_bf16(a[mt], b[nt], acc[mt][nt], 0, 0, 0);
    }
    asm volatile("s_waitcnt vmcnt(0)" ::: "memory");
    __builtin_amdgcn_s_barrier();
    __builtin_amdgcn_sched_barrier(0);
  }

  // epilogue: out[tok, col] += wt * (acc + b2[col])
#pragma unroll
  for (int mt = 0; mt < 8; ++mt)
#pragma unroll
    for (int rr = 0; rr < 4; ++rr) {
      int row = wr * 128 + mt * 16 + lg * 4 + rr;
      if (row < nv) {
        float wt = s_wt[row];
        float* orow = out + (size_t)s_tok[row] * DMODEL;
#pragma unroll
        for (int nt = 0; nt < 4; ++nt)
          atomicAdd(orow + wc * 64 + nt * 16 + l15, wt * (acc[mt][nt][rr] + b2v[nt]));
      }
    }
}

extern "C" void kernel_launch(void* const* d_in, const int* in_sizes, int n_in,
                              void* d_out, int out_size, void* d_ws, size_t ws_size,
                              hipStream_t stream) {
  const float* x    = (const float*)d_in[0];
  const float* gate = (const float*)d_in[1];
  const float* w1   = (const float*)d_in[2];
  const float* b1   = (const float*)d_in[3];
  const float* w2   = (const float*)d_in[4];
  const float* b2   = (const float*)d_in[5];
  float* out = (float*)d_out;
  char* ws = (char*)d_ws;

  unsigned short* xb  = (unsigned short*)(ws);
  unsigned short* P1  = (unsigned short*)(ws + 67108864);
  unsigned short* P2  = (unsigned short*)(ws + 69206016);
  int*    tok_list  = (int*)(ws + 71303168);
  float*  wt_list   = (float*)(ws + 72368128);
  int*    pack      = (int*)(ws + 73433088);
  float2* tkw       = (float2*)(ws + 73957376);
  int*    part_cnt  = (int*)(ws + 75005952);
  float*  part_psum = (float*)(ws + 75071488);
  int*    block_off = (int*)(ws + 75137024);
  int*    cnt_total = (int*)(ws + 75202560);
  unsigned short* Hp = (unsigned short*)(ws + 75497472);

  hipMemsetAsync(d_out, 0, (size_t)out_size * 4, stream);
  k_wconv<<<512, 256, 0, stream>>>(w1, w2, P1, P2);
  k_router<<<2048, 256, 0, stream>>>(x, gate, xb, pack, tkw, part_cnt, part_psum);
  k_scan<<<1, 512, 0, stream>>>(part_cnt, part_psum, block_off, cnt_total, out);
  k_scatter<<<2048, 64, 0, stream>>>(pack, tkw, block_off, cnt_total, tok_list, wt_list);
  k_gemm1<<<4112, 512, 0, stream>>>(xb, P1, b1, tok_list, cnt_total, Hp);
  k_gemm2<<<1032, 512, 0, stream>>>(Hp, P2, b2, tok_list, wt_list, cnt_total, out);
}

// Round 13
// 573.050 us; speedup vs baseline: 1.2691x; 1.2339x over previous
//
#include <hip/hip_runtime.h>

typedef __attribute__((ext_vector_type(8))) short short8;
typedef __attribute__((ext_vector_type(4))) float f32x4;

#define T_TOK  131072
#define DMODEL 256
#define DHID   512
#define NEXP   8

// ---------------- ws layout (bytes) ----------------
// xb        : 0          size 67108864   (T*256 bf16)
// P1        : 67108864   size 2097152    W1 panels [e][kc4][512][64] pre-swizzled
// P2        : 69206016   size 2097152    W2 panels [e][kc8][256][64] pre-swizzled
// tok_list  : 71303168   size 1064960    (padded-base layout)
// wt_list   : 72368128   size 1064960
// pack      : 73433088   size 524288
// tkw/inv   : 73957376   size 1048576    router writes tkw; scatter overwrites with inv[t]={s1,s2}
// part_cnt  : 75005952   size 65536
// part_psum : 75071488   size 65536
// block_off : 75137024   size 65536
// cnt_total : 75202560   size 64         int[16]: counts + 256-PADDED bases
// Hp        : 75497472   size 270532608  H panels [blk][kc8][256][64]; gemm2c reuses
//                                        first half of each block's own panel for Y contribs

__device__ __forceinline__ unsigned short f2bf(float f) {
  unsigned int u = __float_as_uint(f);
  u = (u + 0x7FFFu + ((u >> 16) & 1u)) >> 16;
  return (unsigned short)u;
}
__device__ __forceinline__ float bf2f(unsigned short u) {
  return __uint_as_float(((unsigned)u) << 16);
}

__device__ __forceinline__ void gload16(const void* g, void* l) {
  __builtin_amdgcn_global_load_lds(
      (const __attribute__((address_space(1))) void*)g,
      (__attribute__((address_space(3))) void*)l, 16, 0, 0);
}

// ---------------- weight fp32 -> bf16 K-panels (pre-swizzled) ----------------
__global__ void k_wconv(const float* __restrict__ w1, const float* __restrict__ w2,
                        unsigned short* __restrict__ P1, unsigned short* __restrict__ P2) {
  int g = blockIdx.x * 256 + threadIdx.x;  // 131072 threads
  int e = g >> 14, rem = g & 16383;
  {
    int row = rem >> 5, c = rem & 31;      // 512 rows x 32 chunks (K=256)
    int kc = c >> 3, cs = c & 7;
    const float* s = w1 + ((size_t)e * DHID + row) * DMODEL + c * 8;
    short8 v;
#pragma unroll
    for (int j = 0; j < 8; ++j) v[j] = (short)f2bf(s[j]);
    size_t dc = ((size_t)(e * 4 + kc) * 512 + row) * 8 + (cs ^ (row & 7));
    *(short8*)(P1 + dc * 8) = v;
  }
  {
    int row = rem >> 6, c = rem & 63;      // 256 rows x 64 chunks (K=512)
    int kc = c >> 3, cs = c & 7;
    const float* s = w2 + ((size_t)e * DMODEL + row) * DHID + c * 8;
    short8 v;
#pragma unroll
    for (int j = 0; j < 8; ++j) v[j] = (short)f2bf(s[j]);
    size_t dc = ((size_t)(e * 8 + kc) * 256 + row) * 8 + (cs ^ (row & 7));
    *(short8*)(P2 + dc * 8) = v;
  }
}

// ---------------- router: fp64 logits (bit-identical math), 64 tok/block ----------------
__global__ __launch_bounds__(256) void k_router(
    const float* __restrict__ x, const float* __restrict__ gate,
    unsigned short* __restrict__ xb, int* __restrict__ pack, float2* __restrict__ tkw,
    int* __restrict__ part_cnt, float* __restrict__ part_psum) {
  __shared__ float g[NEXP][DMODEL];
  __shared__ int s_cnt[NEXP];
  __shared__ float s_ps[NEXP];
  int tid = threadIdx.x;
  for (int i = tid; i < NEXP * DMODEL; i += 256) g[i >> 8][i & 255] = gate[i];
  if (tid < NEXP) { s_cnt[tid] = 0; s_ps[tid] = 0.f; }
  __syncthreads();
  int lane = tid & 63, wv = tid >> 6;
  float psacc[NEXP] = {0.f,0.f,0.f,0.f,0.f,0.f,0.f,0.f};
  for (int k = 0; k < 16; ++k) {
    int t = (blockIdx.x << 6) + (wv << 4) + k;
    const float* xr = x + (size_t)t * DMODEL;
    float4 x4 = *(const float4*)(xr + 4 * lane);
    ushort4 u4;
    u4.x = f2bf(x4.x); u4.y = f2bf(x4.y); u4.z = f2bf(x4.z); u4.w = f2bf(x4.w);
    *(ushort4*)(xb + (size_t)t * DMODEL + 4 * lane) = u4;
    double l[NEXP];
#pragma unroll
    for (int e = 0; e < NEXP; ++e) {
      const float4 g4 = *(const float4*)&g[e][4 * lane];
      l[e] = (double)x4.x * (double)g4.x + (double)x4.y * (double)g4.y +
             (double)x4.z * (double)g4.z + (double)x4.w * (double)g4.w;
    }
#pragma unroll
    for (int e = 0; e < NEXP; ++e) {
#pragma unroll
      for (int d = 32; d; d >>= 1) l[e] += __shfl_xor(l[e], d);
    }
    int i1 = 0;
#pragma unroll
    for (int e = 1; e < NEXP; ++e) if (l[e] > l[i1]) i1 = e;
    int i2 = (i1 == 0) ? 1 : 0;
#pragma unroll
    for (int e = 0; e < NEXP; ++e) if (e != i1 && l[e] > l[i2]) i2 = e;
    double m = l[0];
#pragma unroll
    for (int e = 1; e < NEXP; ++e) m = (l[e] > m) ? l[e] : m;
    float pe[NEXP]; float s = 0.f;
#pragma unroll
    for (int e = 0; e < NEXP; ++e) { pe[e] = __expf((float)(l[e] - m)); s += pe[e]; }
    float inv = 1.f / s;
    float p1 = pe[i1] * inv, p2 = pe[i2] * inv;
    float wn = 1.f / (p1 + p2);
    if (lane == 0) {
      pack[t] = i1 | (i2 << 8);
      tkw[t] = make_float2(p1 * wn, p2 * wn);
      atomicAdd(&s_cnt[i1], 1); atomicAdd(&s_cnt[i2], 1);
#pragma unroll
      for (int e = 0; e < NEXP; ++e) psacc[e] += pe[e] * inv;
    }
  }
  if (lane == 0) {
#pragma unroll
    for (int e = 0; e < NEXP; ++e) atomicAdd(&s_ps[e], psacc[e]);
  }
  __syncthreads();
  if (tid < NEXP) {
    part_cnt[blockIdx.x * NEXP + tid] = s_cnt[tid];
    part_psum[blockIdx.x * NEXP + tid] = s_ps[tid];
  }
}

// ---------------- scan: offsets, totals, 256-PADDED expert bases, aux loss ----------------
__global__ __launch_bounds__(512) void k_scan(
    const int* __restrict__ part_cnt, const float* __restrict__ part_psum,
    int* __restrict__ block_off, int* __restrict__ cnt_total, float* __restrict__ out) {
  __shared__ float s_ps[NEXP];
  __shared__ int s_ct[NEXP];
  int lane = threadIdx.x & 63, wv = threadIdx.x >> 6;
  int base = lane * 32;
  int lsum = 0; float ps = 0.f;
#pragma unroll 8
  for (int j = 0; j < 32; ++j) {
    lsum += part_cnt[(base + j) * NEXP + wv];
    ps += part_psum[(base + j) * NEXP + wv];
  }
  int incl = lsum;
#pragma unroll
  for (int d = 1; d < 64; d <<= 1) { int t = __shfl_up(incl, d); if (lane >= d) incl += t; }
  int run = incl - lsum;
#pragma unroll 8
  for (int j = 0; j < 32; ++j) {
    int v = part_cnt[(base + j) * NEXP + wv];
    block_off[(base + j) * NEXP + wv] = run;
    run += v;
  }
#pragma unroll
  for (int d = 32; d; d >>= 1) ps += __shfl_xor(ps, d);
  int total = __shfl(incl, 63);
  if (lane == 0) { cnt_total[wv] = total; s_ct[wv] = total; s_ps[wv] = ps; }
  __syncthreads();
  if (threadIdx.x == 0) {
    double aux = 0.0; int rb = 0;
    for (int e = 0; e < NEXP; ++e) {
      aux += ((double)s_ct[e] / 131072.0) * ((double)s_ps[e] / 131072.0);
      cnt_total[8 + e] = rb;
      rb += (s_ct[e] + 255) & ~255;   // 256-aligned padded base
    }
    out[33554432] = (float)(8.0 * aux);
  }
}

// ---------------- scatter: per-expert lists + inverse map (over tkw, same-type store) ---------
__global__ void k_scatter(const int* __restrict__ pack, float2* tkw,
                          const int* __restrict__ block_off, const int* __restrict__ cnt_total,
                          int* __restrict__ tok_list, float* __restrict__ wt_list) {
  __shared__ int s_loc[NEXP];
  int tid = threadIdx.x;
  if (tid < NEXP) s_loc[tid] = 0;
  __syncthreads();
  int t = (blockIdx.x << 6) + tid;
  int p = pack[t];
  float2 wv = tkw[t];
  int e1 = p & 255, e2 = (p >> 8) & 255;
  int o1 = block_off[blockIdx.x * NEXP + e1];
  int p1 = atomicAdd(&s_loc[e1], 1);
  int i1 = cnt_total[8 + e1] + o1 + p1;
  tok_list[i1] = t; wt_list[i1] = wv.x;
  int o2 = block_off[blockIdx.x * NEXP + e2];
  int p2 = atomicAdd(&s_loc[e2], 1);
  int i2 = cnt_total[8 + e2] + o2 + p2;
  tok_list[i2] = t; wt_list[i2] = wv.y;
  // inverse map: slots of token t (float2 store to same addr keeps load/store ordered)
  tkw[t] = make_float2(__int_as_float(i1), __int_as_float(i2));
}

// ---------------- grouped GEMM1 + silu -> Hp panels (unchanged from R12) ----------------
__global__ __launch_bounds__(512, 2) void k_gemm1(
    const unsigned short* __restrict__ xb, const unsigned short* __restrict__ P1,
    const float* __restrict__ b1, const int* __restrict__ tok_list,
    const int* __restrict__ cnt_total, unsigned short* __restrict__ Hp) {
  __shared__ __align__(16) unsigned short buf[65536];
  __shared__ int s_tok[128];

  int bid = (blockIdx.x & 7) * 514 + (blockIdx.x >> 3);  // grid 4112 = 8*514
  int e = -1, loc = 0, cum = 0, cnte = 0;
#pragma unroll
  for (int ee = 0; ee < NEXP; ++ee) {
    int ct = cnt_total[ee];
    int nb = ((ct + 127) >> 7) * 2;
    if (e < 0 && bid < cum + nb) { e = ee; loc = bid - cum; cnte = ct; }
    cum += nb;
  }
  if (e < 0) return;
  int mi = loc >> 1, ni = loc & 1;
  int nv = cnte - (mi << 7); if (nv > 128) nv = 128;
  int hbp = cnt_total[8 + e];

  int tid = threadIdx.x;
  int lane = tid & 63, w = tid >> 6, l15 = lane & 15, lg = lane >> 4;
  int wr = w >> 2, wc = w & 3;

  float b1v[4];
#pragma unroll
  for (int nt = 0; nt < 4; ++nt)
    b1v[nt] = b1[e * DHID + ni * 256 + wc * 64 + nt * 16 + l15];

  if (tid < 128) s_tok[tid] = tok_list[hbp + (mi << 7) + (tid < nv ? tid : nv - 1)];
  __syncthreads();

#pragma unroll
  for (int i = 0; i < 8; ++i) {
    int cidx = i * 512 + tid;
    int row = cidx >> 5, c = cidx & 31;
    gload16(xb + (size_t)s_tok[row] * DMODEL + (size_t)((c ^ (row & 7)) << 3),
            &buf[(size_t)(i * 512 + w * 64) * 8]);
  }
  auto stage_b = [&](int kc) {
    const unsigned short* src = P1 + ((size_t)(e * 4 + kc) * 512 + ni * 256) * 64;
    int d = 32768 + (kc & 1) * 16384;
#pragma unroll
    for (int i = 0; i < 4; ++i) {
      int cidx = i * 512 + tid;
      gload16(src + (size_t)cidx * 8, &buf[d + (i * 512 + w * 64) * 8]);
    }
  };
  stage_b(0);
  asm volatile("s_waitcnt vmcnt(0)" ::: "memory");
  __builtin_amdgcn_s_barrier();
  __builtin_amdgcn_sched_barrier(0);

  f32x4 acc[4][4];
#pragma unroll
  for (int mt = 0; mt < 4; ++mt)
#pragma unroll
    for (int nt = 0; nt < 4; ++nt) acc[mt][nt] = (f32x4){0.f, 0.f, 0.f, 0.f};

  for (int s = 0; s < 4; ++s) {
    if (s < 3) stage_b(s + 1);
    int bb = 32768 + (s & 1) * 16384;
#pragma unroll
    for (int ks = 0; ks < 2; ++ks) {
      int q = ks * 4 + lg;
      short8 a[4], b[4];
#pragma unroll
      for (int mt = 0; mt < 4; ++mt) {
        int r = wr * 64 + mt * 16 + l15;
        int ch = s * 8 + q;
        a[mt] = *(const short8*)&buf[((size_t)r * 32 + (ch ^ (r & 7))) * 8];
      }
#pragma unroll
      for (int nt = 0; nt < 4; ++nt) {
        int r = wc * 64 + nt * 16 + l15;
        b[nt] = *(const short8*)&buf[bb + ((size_t)r * 8 + (q ^ (r & 7))) * 8];
      }
#pragma unroll
      for (int mt = 0; mt < 4; ++mt)
#pragma unroll
        for (int nt = 0; nt < 4; ++nt)
          acc[mt][nt] = __builtin_amdgcn_mfma_f32_16x16x32_bf16(a[mt], b[nt], acc[mt][nt], 0, 0, 0);
    }
    asm volatile("s_waitcnt vmcnt(0)" ::: "memory");
    __builtin_amdgcn_s_barrier();
    __builtin_amdgcn_sched_barrier(0);
  }

#pragma unroll
  for (int mt = 0; mt < 4; ++mt)
#pragma unroll
    for (int nt = 0; nt < 4; ++nt)
#pragma unroll
      for (int rr = 0; rr < 4; ++rr) {
        int row = wr * 64 + mt * 16 + lg * 4 + rr;
        int col = wc * 64 + nt * 16 + l15;
        float z = acc[mt][nt][rr] + b1v[nt];
        float sv = z / (1.f + __expf(-z));
        buf[(size_t)row * 256 + (((col >> 3) ^ (row & 7)) << 3) + (col & 7)] = f2bf(sv);
      }
  __syncthreads();
  int blk = (hbp >> 8) + (mi >> 1);
  int rbase = (mi & 1) * 128;
#pragma unroll
  for (int i = 0; i < 8; ++i) {
    int cidx = i * 512 + tid;
    int row = cidx >> 5, s32 = cidx & 31;
    int c32 = s32 ^ (row & 7);
    int kc = ni * 4 + (c32 >> 3), cs = c32 & 7;
    short8 v;
    if (row < nv) v = *(const short8*)&buf[(size_t)row * 256 + s32 * 8];
    else { short8 z8 = {0,0,0,0,0,0,0,0}; v = z8; }
    size_t dc = ((size_t)(blk * 8 + kc) * 256 + rbase + row) * 8 + (cs ^ (row & 7));
    *(short8*)&Hp[dc * 8] = v;
  }
}

// ---------------- GEMM2 compute (ABLATION): K-loop identical to R12, epilogue writes
// bf16 contribs wt*(acc+b2) into the FIRST HALF of this block's own Hp panel (all
// panel reads complete before the write; block-exclusive region). NO atomics.
__global__ __launch_bounds__(512, 2) void k_gemm2c(
    unsigned short* Hp, const unsigned short* __restrict__ P2,
    const float* __restrict__ b2, const float* __restrict__ wt_list,
    const int* __restrict__ cnt_total) {
  __shared__ __align__(16) unsigned short buf[65536];
  __shared__ float s_wt[256];

  int bid = (blockIdx.x & 7) * 129 + (blockIdx.x >> 3);  // grid 1032 = 8*129
  int e = -1, mi = 0, cum = 0, cnte = 0;
#pragma unroll
  for (int ee = 0; ee < NEXP; ++ee) {
    int ct = cnt_total[ee];
    int nb = (ct + 255) >> 8;
    if (e < 0 && bid < cum + nb) { e = ee; mi = bid - cum; cnte = ct; }
    cum += nb;
  }
  if (e < 0) return;
  int nv = cnte - (mi << 8); if (nv > 256) nv = 256;
  int hbp = cnt_total[8 + e];
  int blk = (hbp >> 8) + mi;

  int tid = threadIdx.x;
  int lane = tid & 63, w = tid >> 6, l15 = lane & 15, lg = lane >> 4;
  int wr = w >> 2, wc = w & 3;

  float b2v[4];
#pragma unroll
  for (int nt = 0; nt < 4; ++nt)
    b2v[nt] = b2[e * DMODEL + wc * 64 + nt * 16 + l15];

  if (tid < 256) s_wt[tid] = (tid < nv) ? wt_list[hbp + (mi << 8) + tid] : 0.f;
  __syncthreads();

  auto stage = [&](int s) {
    int d = (s & 1) * 32768;
    const unsigned short* sa = Hp + (size_t)(blk * 8 + s) * 16384;
    const unsigned short* sb = P2 + (size_t)(e * 8 + s) * 16384;
#pragma unroll
    for (int i = 0; i < 4; ++i) {
      int c = i * 512 + tid;
      gload16(sa + (size_t)c * 8, &buf[d + (i * 512 + w * 64) * 8]);
    }
#pragma unroll
    for (int i = 0; i < 4; ++i) {
      int c = i * 512 + tid;
      gload16(sb + (size_t)c * 8, &buf[d + 16384 + (i * 512 + w * 64) * 8]);
    }
  };

  f32x4 acc[8][4];
#pragma unroll
  for (int mt = 0; mt < 8; ++mt)
#pragma unroll
    for (int nt = 0; nt < 4; ++nt) acc[mt][nt] = (f32x4){0.f, 0.f, 0.f, 0.f};

  stage(0);
  asm volatile("s_waitcnt vmcnt(0)" ::: "memory");
  __builtin_amdgcn_s_barrier();
  __builtin_amdgcn_sched_barrier(0);

  for (int s = 0; s < 8; ++s) {
    if (s < 7) stage(s + 1);
    int ab = (s & 1) * 32768, bb = ab + 16384;
#pragma unroll
    for (int ks = 0; ks < 2; ++ks) {
      int q = ks * 4 + lg;
      short8 a[8], b[4];
#pragma unroll
      for (int mt = 0; mt < 8; ++mt) {
        int r = wr * 128 + mt * 16 + l15;
        a[mt] = *(const short8*)&buf[ab + ((size_t)r * 8 + (q ^ (r & 7))) * 8];
      }
#pragma unroll
      for (int nt = 0; nt < 4; ++nt) {
        int r = wc * 64 + nt * 16 + l15;
        b[nt] = *(const short8*)&buf[bb + ((size_t)r * 8 + (q ^ (r & 7))) * 8];
      }
#pragma unroll
      for (int mt = 0; mt < 8; ++mt)
#pragma unroll
        for (int nt = 0; nt < 4; ++nt)
          acc[mt][nt] = __builtin_amdgcn_mfma_f32_16x16x32_bf16(a[mt], b[nt], acc[mt][nt], 0, 0, 0);
    }
    asm volatile("s_waitcnt vmcnt(0)" ::: "memory");
    __builtin_amdgcn_s_barrier();
    __builtin_amdgcn_sched_barrier(0);
  }

  // epilogue: contribs -> LDS (linear) -> streaming bf16 store into own panel's first half
#pragma unroll
  for (int mt = 0; mt < 8; ++mt)
#pragma unroll
    for (int nt = 0; nt < 4; ++nt)
#pragma unroll
      for (int rr = 0; rr < 4; ++rr) {
        int row = wr * 128 + mt * 16 + lg * 4 + rr;
        int col = wc * 64 + nt * 16 + l15;
        buf[(size_t)row * 256 + col] = f2bf(s_wt[row] * (acc[mt][nt][rr] + b2v[nt]));
      }
  __syncthreads();
  unsigned short* ydst = Hp + (size_t)blk * 131072;
#pragma unroll
  for (int i = 0; i < 16; ++i) {
    size_t cidx = (size_t)(i * 512 + tid) * 8;
    *(short8*)&ydst[cidx] = *(const short8*)&buf[cidx];
  }
}

// ---------------- reduce: out[t] = Y[s1] + Y[s2] (no atomics, writes every element) -------
__global__ __launch_bounds__(256) void k_reduce(
    const unsigned short* __restrict__ Y, const float2* __restrict__ inv,
    float* __restrict__ out) {
  int g = blockIdx.x * 256 + threadIdx.x;
#pragma unroll
  for (int it = 0; it < 8; ++it) {
    int t = g >> 5;
    int cw = (g & 31) << 3;
    float2 iv = inv[t];
    int s1 = __float_as_int(iv.x), s2 = __float_as_int(iv.y);
    const unsigned short* y1 = Y + (size_t)(s1 >> 8) * 131072 + (size_t)(s1 & 255) * 256 + cw;
    const unsigned short* y2 = Y + (size_t)(s2 >> 8) * 131072 + (size_t)(s2 & 255) * 256 + cw;
    short8 a = *(const short8*)y1;
    short8 b = *(const short8*)y2;
    float* op = out + (size_t)t * 256 + cw;
    float4 r0, r1;
    r0.x = bf2f((unsigned short)a[0]) + bf2f((unsigned short)b[0]);
    r0.y = bf2f((unsigned short)a[1]) + bf2f((unsigned short)b[1]);
    r0.z = bf2f((unsigned short)a[2]) + bf2f((unsigned short)b[2]);
    r0.w = bf2f((unsigned short)a[3]) + bf2f((unsigned short)b[3]);
    r1.x = bf2f((unsigned short)a[4]) + bf2f((unsigned short)b[4]);
    r1.y = bf2f((unsigned short)a[5]) + bf2f((unsigned short)b[5]);
    r1.z = bf2f((unsigned short)a[6]) + bf2f((unsigned short)b[6]);
    r1.w = bf2f((unsigned short)a[7]) + bf2f((unsigned short)b[7]);
    *(float4*)op = r0;
    *(float4*)(op + 4) = r1;
    g += 2048 * 256;
  }
}

extern "C" void kernel_launch(void* const* d_in, const int* in_sizes, int n_in,
                              void* d_out, int out_size, void* d_ws, size_t ws_size,
                              hipStream_t stream) {
  const float* x    = (const float*)d_in[0];
  const float* gate = (const float*)d_in[1];
  const float* w1   = (const float*)d_in[2];
  const float* b1   = (const float*)d_in[3];
  const float* w2   = (const float*)d_in[4];
  const float* b2   = (const float*)d_in[5];
  float* out = (float*)d_out;
  char* ws = (char*)d_ws;

  unsigned short* xb  = (unsigned short*)(ws);
  unsigned short* P1  = (unsigned short*)(ws + 67108864);
  unsigned short* P2  = (unsigned short*)(ws + 69206016);
  int*    tok_list  = (int*)(ws + 71303168);
  float*  wt_list   = (float*)(ws + 72368128);
  int*    pack      = (int*)(ws + 73433088);
  float2* tkw       = (float2*)(ws + 73957376);
  int*    part_cnt  = (int*)(ws + 75005952);
  float*  part_psum = (float*)(ws + 75071488);
  int*    block_off = (int*)(ws + 75137024);
  int*    cnt_total = (int*)(ws + 75202560);
  unsigned short* Hp = (unsigned short*)(ws + 75497472);

  k_wconv<<<512, 256, 0, stream>>>(w1, w2, P1, P2);
  k_router<<<2048, 256, 0, stream>>>(x, gate, xb, pack, tkw, part_cnt, part_psum);
  k_scan<<<1, 512, 0, stream>>>(part_cnt, part_psum, block_off, cnt_total, out);
  k_scatter<<<2048, 64, 0, stream>>>(pack, tkw, block_off, cnt_total, tok_list, wt_list);
  k_gemm1<<<4112, 512, 0, stream>>>(xb, P1, b1, tok_list, cnt_total, Hp);
  k_gemm2c<<<1032, 512, 0, stream>>>(Hp, P2, b2, wt_list, cnt_total);
  k_reduce<<<2048, 256, 0, stream>>>(Hp, tkw, out);
}

// Round 15
// 546.148 us; speedup vs baseline: 1.3316x; 1.0493x over previous
//
#include <hip/hip_runtime.h>

typedef __attribute__((ext_vector_type(8))) short short8;
typedef __attribute__((ext_vector_type(4))) float f32x4;

#define T_TOK  131072
#define DMODEL 256
#define DHID   512
#define NEXP   8

// ---------------- ws layout (bytes) ----------------
// xb        : 0          size 67108864   (T*256 bf16)
// P1        : 67108864   size 2097152    W1 panels [e][kc4][512][64] pre-swizzled
// P2        : 69206016   size 2097152    W2 panels [e][kc8][256][64] pre-swizzled
// tok_list  : 71303168   size 1064960    (padded-base layout)
// wt_list   : 72368128   size 1064960
// pack      : 73433088   size 524288
// tkw/inv   : 73957376   size 1048576    router writes tkw; scatter overwrites with inv[t]={s1,s2}
// part_cnt  : 75005952   size 65536
// part_psum : 75071488   size 65536
// block_off : 75137024   size 65536
// cnt_total : 75202560   size 64         int[16]: counts + 256-PADDED bases
// Hp        : 75497472   size 270532608  H panels [blk][kc8][256][64]; gemm2c reuses
//                                        first half of each block's own panel for Y contribs

__device__ __forceinline__ unsigned short f2bf(float f) {
  unsigned int u = __float_as_uint(f);
  u = (u + 0x7FFFu + ((u >> 16) & 1u)) >> 16;
  return (unsigned short)u;
}
__device__ __forceinline__ float bf2f(unsigned short u) {
  return __uint_as_float(((unsigned)u) << 16);
}

__device__ __forceinline__ void gload16(const void* g, void* l) {
  __builtin_amdgcn_global_load_lds(
      (const __attribute__((address_space(1))) void*)g,
      (__attribute__((address_space(3))) void*)l, 16, 0, 0);
}

// ---------------- weight fp32 -> bf16 K-panels (pre-swizzled, RNE) ----------------
__global__ void k_wconv(const float* __restrict__ w1, const float* __restrict__ w2,
                        unsigned short* __restrict__ P1, unsigned short* __restrict__ P2) {
  int g = blockIdx.x * 256 + threadIdx.x;  // 131072 threads
  int e = g >> 14, rem = g & 16383;
  {
    int row = rem >> 5, c = rem & 31;      // 512 rows x 32 chunks (K=256)
    int kc = c >> 3, cs = c & 7;
    const float* s = w1 + ((size_t)e * DHID + row) * DMODEL + c * 8;
    short8 v;
#pragma unroll
    for (int j = 0; j < 8; ++j) v[j] = (short)f2bf(s[j]);
    size_t dc = ((size_t)(e * 4 + kc) * 512 + row) * 8 + (cs ^ (row & 7));
    *(short8*)(P1 + dc * 8) = v;
  }
  {
    int row = rem >> 6, c = rem & 63;      // 256 rows x 64 chunks (K=512)
    int kc = c >> 3, cs = c & 7;
    const float* s = w2 + ((size_t)e * DMODEL + row) * DHID + c * 8;
    short8 v;
#pragma unroll
    for (int j = 0; j < 8; ++j) v[j] = (short)f2bf(s[j]);
    size_t dc = ((size_t)(e * 8 + kc) * 256 + row) * 8 + (cs ^ (row & 7));
    *(short8*)(P2 + dc * 8) = v;
  }
}

// ---------------- router: fp64 logits (bit-identical math), 64 tok/block ----------------
__global__ __launch_bounds__(256) void k_router(
    const float* __restrict__ x, const float* __restrict__ gate,
    unsigned short* __restrict__ xb, int* __restrict__ pack, float2* __restrict__ tkw,
    int* __restrict__ part_cnt, float* __restrict__ part_psum) {
  __shared__ float g[NEXP][DMODEL];
  __shared__ int s_cnt[NEXP];
  __shared__ float s_ps[NEXP];
  int tid = threadIdx.x;
  for (int i = tid; i < NEXP * DMODEL; i += 256) g[i >> 8][i & 255] = gate[i];
  if (tid < NEXP) { s_cnt[tid] = 0; s_ps[tid] = 0.f; }
  __syncthreads();
  int lane = tid & 63, wv = tid >> 6;
  float psacc[NEXP] = {0.f,0.f,0.f,0.f,0.f,0.f,0.f,0.f};
  for (int k = 0; k < 16; ++k) {
    int t = (blockIdx.x << 6) + (wv << 4) + k;
    const float* xr = x + (size_t)t * DMODEL;
    float4 x4 = *(const float4*)(xr + 4 * lane);
    ushort4 u4;
    u4.x = f2bf(x4.x); u4.y = f2bf(x4.y); u4.z = f2bf(x4.z); u4.w = f2bf(x4.w);
    *(ushort4*)(xb + (size_t)t * DMODEL + 4 * lane) = u4;
    double l[NEXP];
#pragma unroll
    for (int e = 0; e < NEXP; ++e) {
      const float4 g4 = *(const float4*)&g[e][4 * lane];
      l[e] = (double)x4.x * (double)g4.x + (double)x4.y * (double)g4.y +
             (double)x4.z * (double)g4.z + (double)x4.w * (double)g4.w;
    }
#pragma unroll
    for (int e = 0; e < NEXP; ++e) {
#pragma unroll
      for (int d = 32; d; d >>= 1) l[e] += __shfl_xor(l[e], d);
    }
    int i1 = 0;
#pragma unroll
    for (int e = 1; e < NEXP; ++e) if (l[e] > l[i1]) i1 = e;
    int i2 = (i1 == 0) ? 1 : 0;
#pragma unroll
    for (int e = 0; e < NEXP; ++e) if (e != i1 && l[e] > l[i2]) i2 = e;
    double m = l[0];
#pragma unroll
    for (int e = 1; e < NEXP; ++e) m = (l[e] > m) ? l[e] : m;
    float pe[NEXP]; float s = 0.f;
#pragma unroll
    for (int e = 0; e < NEXP; ++e) { pe[e] = __expf((float)(l[e] - m)); s += pe[e]; }
    float inv = 1.f / s;
    float p1 = pe[i1] * inv, p2 = pe[i2] * inv;
    float wn = 1.f / (p1 + p2);
    if (lane == 0) {
      pack[t] = i1 | (i2 << 8);
      tkw[t] = make_float2(p1 * wn, p2 * wn);
      atomicAdd(&s_cnt[i1], 1); atomicAdd(&s_cnt[i2], 1);
#pragma unroll
      for (int e = 0; e < NEXP; ++e) psacc[e] += pe[e] * inv;
    }
  }
  if (lane == 0) {
#pragma unroll
    for (int e = 0; e < NEXP; ++e) atomicAdd(&s_ps[e], psacc[e]);
  }
  __syncthreads();
  if (tid < NEXP) {
    part_cnt[blockIdx.x * NEXP + tid] = s_cnt[tid];
    part_psum[blockIdx.x * NEXP + tid] = s_ps[tid];
  }
}

// ---------------- scan: offsets, totals, 256-PADDED expert bases, aux loss ----------------
__global__ __launch_bounds__(512) void k_scan(
    const int* __restrict__ part_cnt, const float* __restrict__ part_psum,
    int* __restrict__ block_off, int* __restrict__ cnt_total, float* __restrict__ out) {
  __shared__ float s_ps[NEXP];
  __shared__ int s_ct[NEXP];
  int lane = threadIdx.x & 63, wv = threadIdx.x >> 6;
  int base = lane * 32;
  int lsum = 0; float ps = 0.f;
#pragma unroll 8
  for (int j = 0; j < 32; ++j) {
    lsum += part_cnt[(base + j) * NEXP + wv];
    ps += part_psum[(base + j) * NEXP + wv];
  }
  int incl = lsum;
#pragma unroll
  for (int d = 1; d < 64; d <<= 1) { int t = __shfl_up(incl, d); if (lane >= d) incl += t; }
  int run = incl - lsum;
#pragma unroll 8
  for (int j = 0; j < 32; ++j) {
    int v = part_cnt[(base + j) * NEXP + wv];
    block_off[(base + j) * NEXP + wv] = run;
    run += v;
  }
#pragma unroll
  for (int d = 32; d; d >>= 1) ps += __shfl_xor(ps, d);
  int total = __shfl(incl, 63);
  if (lane == 0) { cnt_total[wv] = total; s_ct[wv] = total; s_ps[wv] = ps; }
  __syncthreads();
  if (threadIdx.x == 0) {
    double aux = 0.0; int rb = 0;
    for (int e = 0; e < NEXP; ++e) {
      aux += ((double)s_ct[e] / 131072.0) * ((double)s_ps[e] / 131072.0);
      cnt_total[8 + e] = rb;
      rb += (s_ct[e] + 255) & ~255;   // 256-aligned padded base
    }
    out[33554432] = (float)(8.0 * aux);
  }
}

// ---------------- scatter: per-expert lists + inverse map (over tkw) ----------------
__global__ void k_scatter(const int* __restrict__ pack, float2* tkw,
                          const int* __restrict__ block_off, const int* __restrict__ cnt_total,
                          int* __restrict__ tok_list, float* __restrict__ wt_list) {
  __shared__ int s_loc[NEXP];
  int tid = threadIdx.x;
  if (tid < NEXP) s_loc[tid] = 0;
  __syncthreads();
  int t = (blockIdx.x << 6) + tid;
  int p = pack[t];
  float2 wv = tkw[t];
  int e1 = p & 255, e2 = (p >> 8) & 255;
  int o1 = block_off[blockIdx.x * NEXP + e1];
  int p1 = atomicAdd(&s_loc[e1], 1);
  int i1 = cnt_total[8 + e1] + o1 + p1;
  tok_list[i1] = t; wt_list[i1] = wv.x;
  int o2 = block_off[blockIdx.x * NEXP + e2];
  int p2 = atomicAdd(&s_loc[e2], 1);
  int i2 = cnt_total[8 + e2] + o2 + p2;
  tok_list[i2] = t; wt_list[i2] = wv.y;
  tkw[t] = make_float2(__int_as_float(i1), __int_as_float(i2));
}

// ---------------- grouped GEMM1 + silu -> Hp panels (VALU-lean) ----------------
// R14 BUG FIX: silu-store XOR must use (lg*4+rr)&7, not the 4-bit lg*4+rr.
__global__ __launch_bounds__(512, 2) void k_gemm1(
    const unsigned short* __restrict__ xb, const unsigned short* __restrict__ P1,
    const float* __restrict__ b1, const int* __restrict__ tok_list,
    const int* __restrict__ cnt_total, unsigned short* __restrict__ Hp) {
  __shared__ __align__(16) unsigned short buf[65536];
  __shared__ int s_tok[128];

  int bid = (blockIdx.x & 7) * 514 + (blockIdx.x >> 3);  // grid 4112 = 8*514
  int e = -1, loc = 0, cum = 0, cnte = 0;
#pragma unroll
  for (int ee = 0; ee < NEXP; ++ee) {
    int ct = cnt_total[ee];
    int nb = ((ct + 127) >> 7) * 2;
    if (e < 0 && bid < cum + nb) { e = ee; loc = bid - cum; cnte = ct; }
    cum += nb;
  }
  if (e < 0) return;
  int mi = loc >> 1, ni = loc & 1;
  int nv = cnte - (mi << 7); if (nv > 128) nv = 128;
  int hbp = cnt_total[8 + e];

  int tid = threadIdx.x;
  int lane = tid & 63, w = tid >> 6, l15 = lane & 15, lg = lane >> 4;
  int wr = w >> 2, wc = w & 3;

  float b1v[4];
#pragma unroll
  for (int nt = 0; nt < 4; ++nt)
    b1v[nt] = b1[e * DHID + ni * 256 + wc * 64 + nt * 16 + l15];

  if (tid < 128) s_tok[tid] = tok_list[hbp + (mi << 7) + (tid < nv ? tid : nv - 1)];
  __syncthreads();

  // stage A: full K; row = i*16 + ar0, chunk-slot = tid&31 (const), swz const
  int ar0 = tid >> 5;
  int ac = tid & 31;
#pragma unroll
  for (int i = 0; i < 8; ++i) {
    int row = i * 16 + ar0;
    gload16(xb + (size_t)s_tok[row] * DMODEL + (size_t)((ac ^ (row & 7)) << 3),
            &buf[(size_t)(i * 512 + w * 64) * 8]);
  }
  auto stage_b = [&](int kc) {
    const unsigned short* src = P1 + ((size_t)(e * 4 + kc) * 512 + ni * 256) * 64;
    int d = 32768 + (kc & 1) * 16384;
#pragma unroll
    for (int i = 0; i < 4; ++i) {
      int cidx = i * 512 + tid;
      gload16(src + (size_t)cidx * 8, &buf[d + (i * 512 + w * 64) * 8]);
    }
  };
  stage_b(0);
  asm volatile("s_waitcnt vmcnt(0)" ::: "memory");
  __builtin_amdgcn_s_barrier();
  __builtin_amdgcn_sched_barrier(0);

  // precomputed per-thread u16 LDS indices (step part added in-loop)
  int aidx[4][2], bidx[4][2];
#pragma unroll
  for (int mt = 0; mt < 4; ++mt) {
    int r = wr * 64 + mt * 16 + l15, r7 = r & 7;
#pragma unroll
    for (int ks = 0; ks < 2; ++ks) aidx[mt][ks] = r * 256 + (((ks * 4 + lg) ^ r7) << 3);
  }
#pragma unroll
  for (int nt = 0; nt < 4; ++nt) {
    int r = wc * 64 + nt * 16 + l15, r7 = r & 7;
#pragma unroll
    for (int ks = 0; ks < 2; ++ks) bidx[nt][ks] = r * 64 + (((ks * 4 + lg) ^ r7) << 3);
  }

  f32x4 acc[4][4];
#pragma unroll
  for (int mt = 0; mt < 4; ++mt)
#pragma unroll
    for (int nt = 0; nt < 4; ++nt) acc[mt][nt] = (f32x4){0.f, 0.f, 0.f, 0.f};

  for (int s = 0; s < 4; ++s) {
    if (s < 3) stage_b(s + 1);
    int abase = s * 64;                      // A: +s*64 u16 per step
    int bbase = 32768 + (s & 1) * 16384;
#pragma unroll
    for (int ks = 0; ks < 2; ++ks) {
      short8 a[4], b[4];
#pragma unroll
      for (int mt = 0; mt < 4; ++mt) a[mt] = *(const short8*)&buf[abase + aidx[mt][ks]];
#pragma unroll
      for (int nt = 0; nt < 4; ++nt) b[nt] = *(const short8*)&buf[bbase + bidx[nt][ks]];
#pragma unroll
      for (int mt = 0; mt < 4; ++mt)
#pragma unroll
        for (int nt = 0; nt < 4; ++nt)
          acc[mt][nt] = __builtin_amdgcn_mfma_f32_16x16x32_bf16(a[mt], b[nt], acc[mt][nt], 0, 0, 0);
    }
    asm volatile("s_waitcnt vmcnt(0)" ::: "memory");
    __builtin_amdgcn_s_barrier();
    __builtin_amdgcn_sched_barrier(0);
  }

  // epilogue: fast silu (v_rcp), truncation bf16; XOR uses row&7 = (lg*4+rr)&7
#pragma unroll
  for (int mt = 0; mt < 4; ++mt) {
    int rbase0 = (wr * 64 + mt * 16) * 256;
#pragma unroll
    for (int nt = 0; nt < 4; ++nt) {
      int col = wc * 64 + nt * 16 + l15;
      int c3 = col >> 3, c7 = col & 7;
#pragma unroll
      for (int rr = 0; rr < 4; ++rr) {
        int lr = lg * 4 + rr;                // local row 0..15
        int r7 = lr & 7;                     // row&7 (FIX: mask to 3 bits)
        float z = acc[mt][nt][rr] + b1v[nt];
        float sv = z * __builtin_amdgcn_rcpf(1.f + __expf(-z));
        buf[rbase0 + lr * 256 + ((c3 ^ r7) << 3) + c7] =
            (unsigned short)(__float_as_uint(sv) >> 16);
      }
    }
  }
  __syncthreads();
  int blk = (hbp >> 8) + (mi >> 1);
  int rbase = (mi & 1) * 128;
  {
    int s32 = tid & 31;
    int c32 = s32 ^ (ar0 & 7);               // constant per thread
    int kc = ni * 4 + (c32 >> 3), cs = c32 & 7;
    size_t gb = (((size_t)(blk * 8 + kc) * 256 + rbase + ar0) * 8 + (size_t)(cs ^ (ar0 & 7))) * 8;
    int lb = ar0 * 256 + s32 * 8;
    short8 z8 = {0, 0, 0, 0, 0, 0, 0, 0};
#pragma unroll
    for (int i = 0; i < 8; ++i) {
      int row = i * 16 + ar0;
      short8 v = (row < nv) ? *(const short8*)&buf[lb + i * 4096] : z8;
      *(short8*)&Hp[gb + (size_t)i * 1024] = v;   // +16 rows * 8 slots * 8 u16
    }
  }
}

// ---------------- GEMM2 compute: K-loop w/ precomputed indices, trunc epilogue ----------
__global__ __launch_bounds__(512, 2) void k_gemm2c(
    unsigned short* Hp, const unsigned short* __restrict__ P2,
    const float* __restrict__ b2, const float* __restrict__ wt_list,
    const int* __restrict__ cnt_total) {
  __shared__ __align__(16) unsigned short buf[65536];
  __shared__ float s_wt[256];

  int bid = (blockIdx.x & 7) * 129 + (blockIdx.x >> 3);  // grid 1032 = 8*129
  int e = -1, mi = 0, cum = 0, cnte = 0;
#pragma unroll
  for (int ee = 0; ee < NEXP; ++ee) {
    int ct = cnt_total[ee];
    int nb = (ct + 255) >> 8;
    if (e < 0 && bid < cum + nb) { e = ee; mi = bid - cum; cnte = ct; }
    cum += nb;
  }
  if (e < 0) return;
  int nv = cnte - (mi << 8); if (nv > 256) nv = 256;
  int hbp = cnt_total[8 + e];
  int blk = (hbp >> 8) + mi;

  int tid = threadIdx.x;
  int lane = tid & 63, w = tid >> 6, l15 = lane & 15, lg = lane >> 4;
  int wr = w >> 2, wc = w & 3;

  float b2v[4];
#pragma unroll
  for (int nt = 0; nt < 4; ++nt)
    b2v[nt] = b2[e * DMODEL + wc * 64 + nt * 16 + l15];

  if (tid < 256) s_wt[tid] = (tid < nv) ? wt_list[hbp + (mi << 8) + tid] : 0.f;
  __syncthreads();

  auto stage = [&](int s) {
    int d = (s & 1) * 32768;
    const unsigned short* sa = Hp + (size_t)(blk * 8 + s) * 16384;
    const unsigned short* sb = P2 + (size_t)(e * 8 + s) * 16384;
#pragma unroll
    for (int i = 0; i < 4; ++i) {
      int c = i * 512 + tid;
      gload16(sa + (size_t)c * 8, &buf[d + (i * 512 + w * 64) * 8]);
    }
#pragma unroll
    for (int i = 0; i < 4; ++i) {
      int c = i * 512 + tid;
      gload16(sb + (size_t)c * 8, &buf[d + 16384 + (i * 512 + w * 64) * 8]);
    }
  };

  // precomputed per-thread u16 LDS indices
  int aidx[8][2], bidx[4][2];
#pragma unroll
  for (int mt = 0; mt < 8; ++mt) {
    int r = wr * 128 + mt * 16 + l15, r7 = r & 7;
#pragma unroll
    for (int ks = 0; ks < 2; ++ks) aidx[mt][ks] = r * 64 + (((ks * 4 + lg) ^ r7) << 3);
  }
#pragma unroll
  for (int nt = 0; nt < 4; ++nt) {
    int r = wc * 64 + nt * 16 + l15, r7 = r & 7;
#pragma unroll
    for (int ks = 0; ks < 2; ++ks) bidx[nt][ks] = r * 64 + (((ks * 4 + lg) ^ r7) << 3);
  }

  f32x4 acc[8][4];
#pragma unroll
  for (int mt = 0; mt < 8; ++mt)
#pragma unroll
    for (int nt = 0; nt < 4; ++nt) acc[mt][nt] = (f32x4){0.f, 0.f, 0.f, 0.f};

  stage(0);
  asm volatile("s_waitcnt vmcnt(0)" ::: "memory");
  __builtin_amdgcn_s_barrier();
  __builtin_amdgcn_sched_barrier(0);

  for (int s = 0; s < 8; ++s) {
    if (s < 7) stage(s + 1);
    int ab = (s & 1) * 32768, bb = ab + 16384;
#pragma unroll
    for (int ks = 0; ks < 2; ++ks) {
      short8 a[8], b[4];
#pragma unroll
      for (int mt = 0; mt < 8; ++mt) a[mt] = *(const short8*)&buf[ab + aidx[mt][ks]];
#pragma unroll
      for (int nt = 0; nt < 4; ++nt) b[nt] = *(const short8*)&buf[bb + bidx[nt][ks]];
#pragma unroll
      for (int mt = 0; mt < 8; ++mt)
#pragma unroll
        for (int nt = 0; nt < 4; ++nt)
          acc[mt][nt] = __builtin_amdgcn_mfma_f32_16x16x32_bf16(a[mt], b[nt], acc[mt][nt], 0, 0, 0);
    }
    asm volatile("s_waitcnt vmcnt(0)" ::: "memory");
    __builtin_amdgcn_s_barrier();
    __builtin_amdgcn_sched_barrier(0);
  }

  // epilogue: contribs -> LDS (linear) -> streaming bf16 store into own panel's first half
#pragma unroll
  for (int mt = 0; mt < 8; ++mt) {
    int rbase0 = (wr * 128 + mt * 16) * 256;
#pragma unroll
    for (int nt = 0; nt < 4; ++nt) {
      int col = wc * 64 + nt * 16 + l15;
#pragma unroll
      for (int rr = 0; rr < 4; ++rr) {
        int row = wr * 128 + mt * 16 + lg * 4 + rr;
        float v = s_wt[row] * (acc[mt][nt][rr] + b2v[nt]);
        buf[rbase0 + (lg * 4 + rr) * 256 + col] =
            (unsigned short)(__float_as_uint(v) >> 16);
      }
    }
  }
  __syncthreads();
  unsigned short* ydst = Hp + (size_t)blk * 131072;
#pragma unroll
  for (int i = 0; i < 16; ++i) {
    size_t cidx = (size_t)(i * 512 + tid) * 8;
    *(short8*)&ydst[cidx] = *(const short8*)&buf[cidx];
  }
}

// ---------------- reduce: out[t] = Y[s1] + Y[s2] ----------------
__global__ __launch_bounds__(256) void k_reduce(
    const unsigned short* __restrict__ Y, const float2* __restrict__ inv,
    float* __restrict__ out) {
  int g = blockIdx.x * 256 + threadIdx.x;
#pragma unroll
  for (int it = 0; it < 8; ++it) {
    int t = g >> 5;
    int cw = (g & 31) << 3;
    float2 iv = inv[t];
    int s1 = __float_as_int(iv.x), s2 = __float_as_int(iv.y);
    const unsigned short* y1 = Y + (size_t)(s1 >> 8) * 131072 + (size_t)(s1 & 255) * 256 + cw;
    const unsigned short* y2 = Y + (size_t)(s2 >> 8) * 131072 + (size_t)(s2 & 255) * 256 + cw;
    short8 a = *(const short8*)y1;
    short8 b = *(const short8*)y2;
    float* op = out + (size_t)t * 256 + cw;
    float4 r0, r1;
    r0.x = bf2f((unsigned short)a[0]) + bf2f((unsigned short)b[0]);
    r0.y = bf2f((unsigned short)a[1]) + bf2f((unsigned short)b[1]);
    r0.z = bf2f((unsigned short)a[2]) + bf2f((unsigned short)b[2]);
    r0.w = bf2f((unsigned short)a[3]) + bf2f((unsigned short)b[3]);
    r1.x = bf2f((unsigned short)a[4]) + bf2f((unsigned short)b[4]);
    r1.y = bf2f((unsigned short)a[5]) + bf2f((unsigned short)b[5]);
    r1.z = bf2f((unsigned short)a[6]) + bf2f((unsigned short)b[6]);
    r1.w = bf2f((unsigned short)a[7]) + bf2f((unsigned short)b[7]);
    *(float4*)op = r0;
    *(float4*)(op + 4) = r1;
    g += 2048 * 256;
  }
}

extern "C" void kernel_launch(void* const* d_in, const int* in_sizes, int n_in,
                              void* d_out, int out_size, void* d_ws, size_t ws_size,
                              hipStream_t stream) {
  const float* x    = (const float*)d_in[0];
  const float* gate = (const float*)d_in[1];
  const float* w1   = (const float*)d_in[2];
  const float* b1   = (const float*)d_in[3];
  const float* w2   = (const float*)d_in[4];
  const float* b2   = (const float*)d_in[5];
  float* out = (float*)d_out;
  char* ws = (char*)d_ws;

  unsigned short* xb  = (unsigned short*)(ws);
  unsigned short* P1  = (unsigned short*)(ws + 67108864);
  unsigned short* P2  = (unsigned short*)(ws + 69206016);
  int*    tok_list  = (int*)(ws + 71303168);
  float*  wt_list   = (float*)(ws + 72368128);
  int*    pack      = (int*)(ws + 73433088);
  float2* tkw       = (float2*)(ws + 73957376);
  int*    part_cnt  = (int*)(ws + 75005952);
  float*  part_psum = (float*)(ws + 75071488);
  int*    block_off = (int*)(ws + 75137024);
  int*    cnt_total = (int*)(ws + 75202560);
  unsigned short* Hp = (unsigned short*)(ws + 75497472);

  k_wconv<<<512, 256, 0, stream>>>(w1, w2, P1, P2);
  k_router<<<2048, 256, 0, stream>>>(x, gate, xb, pack, tkw, part_cnt, part_psum);
  k_scan<<<1, 512, 0, stream>>>(part_cnt, part_psum, block_off, cnt_total, out);
  k_scatter<<<2048, 64, 0, stream>>>(pack, tkw, block_off, cnt_total, tok_list, wt_list);
  k_gemm1<<<4112, 512, 0, stream>>>(xb, P1, b1, tok_list, cnt_total, Hp);
  k_gemm2c<<<1032, 512, 0, stream>>>(Hp, P2, b2, wt_list, cnt_total);
  k_reduce<<<2048, 256, 0, stream>>>(Hp, tkw, out);
}

// Round 16
// 503.613 us; speedup vs baseline: 1.4441x; 1.0845x over previous
//
#include <hip/hip_runtime.h>

typedef __attribute__((ext_vector_type(8))) short short8;
typedef __attribute__((ext_vector_type(4))) float f32x4;

#define T_TOK  131072
#define DMODEL 256
#define DHID   512
#define NEXP   8

// ---------------- ws layout (bytes) ----------------
// xb        : 0          size 67108864   (T*256 bf16)
// P1        : 67108864   size 2097152    W1 panels [e][kc4][512][64] pre-swizzled
// P2        : 69206016   size 2097152    W2 panels [e][kc8][256][64] pre-swizzled
// tok_list  : 71303168   size 1064960    (padded-base layout)
// wt_list   : 72368128   size 1064960
// pack      : 73433088   size 524288
// tkw/inv   : 73957376   size 1048576
// part_cnt  : 75005952   size 65536
// part_psum : 75071488   size 65536
// block_off : 75137024   size 65536
// cnt_total : 75202560   size 64         int[16]: counts + 256-PADDED bases
// gate_d    : 75235328   size 16384      gate as fp64 [8][256]
// Hp        : 75497472   size 270532608  H panels; gemm2c reuses first half for Y

__device__ __forceinline__ unsigned short f2bf(float f) {
  unsigned int u = __float_as_uint(f);
  u = (u + 0x7FFFu + ((u >> 16) & 1u)) >> 16;
  return (unsigned short)u;
}
__device__ __forceinline__ float bf2f(unsigned short u) {
  return __uint_as_float(((unsigned)u) << 16);
}

__device__ __forceinline__ void gload16(const void* g, void* l) {
  __builtin_amdgcn_global_load_lds(
      (const __attribute__((address_space(1))) void*)g,
      (__attribute__((address_space(3))) void*)l, 16, 0, 0);
}

// ---------------- weight fp32 -> bf16 K-panels (pre-swizzled) + gate fp64 ----------------
__global__ void k_wconv(const float* __restrict__ w1, const float* __restrict__ w2,
                        const float* __restrict__ gate,
                        unsigned short* __restrict__ P1, unsigned short* __restrict__ P2,
                        double* __restrict__ gate_d) {
  int g = blockIdx.x * 256 + threadIdx.x;  // 131072 threads
  if (g < 2048) gate_d[g] = (double)gate[g];
  int e = g >> 14, rem = g & 16383;
  {
    int row = rem >> 5, c = rem & 31;      // 512 rows x 32 chunks (K=256)
    int kc = c >> 3, cs = c & 7;
    const float* s = w1 + ((size_t)e * DHID + row) * DMODEL + c * 8;
    short8 v;
#pragma unroll
    for (int j = 0; j < 8; ++j) v[j] = (short)f2bf(s[j]);
    size_t dc = ((size_t)(e * 4 + kc) * 512 + row) * 8 + (cs ^ (row & 7));
    *(short8*)(P1 + dc * 8) = v;
  }
  {
    int row = rem >> 6, c = rem & 63;      // 256 rows x 64 chunks (K=512)
    int kc = c >> 3, cs = c & 7;
    const float* s = w2 + ((size_t)e * DMODEL + row) * DHID + c * 8;
    short8 v;
#pragma unroll
    for (int j = 0; j < 8; ++j) v[j] = (short)f2bf(s[j]);
    size_t dc = ((size_t)(e * 8 + kc) * 256 + row) * 8 + (cs ^ (row & 7));
    *(short8*)(P2 + dc * 8) = v;
  }
}

// ---------------- router: token-per-lane, fp64 logits via s_load'd gate_d ----------------
// 512 blocks x 256 thr; block = 256 tokens in 4 chunks of 64. Per chunk: stage
// x rows to LDS (XOR-swizzled d^(row&31): column reads conflict-free), each
// thread (tok, quarter) computes fp64 partials for its token; combine via LDS;
// 64 threads finalize selection per-thread (NO shuffles). Hist granularity
// stays 64 tokens: part index = blockIdx*4 + c (k_scan/k_scatter unchanged).
__global__ __launch_bounds__(256, 2) void k_router(
    const float* __restrict__ x, const double* __restrict__ gd,
    unsigned short* __restrict__ xb, int* __restrict__ pack, float2* __restrict__ tkw,
    int* __restrict__ part_cnt, float* __restrict__ part_psum) {
  __shared__ float xs[16384];       // 64 rows x 256 (swizzled slots), 64KB
  __shared__ double red[1024];      // 256 thr x 4 experts, 8KB
  __shared__ int s_cnt[NEXP];
  __shared__ float s_ps[NEXP];
  int tid = threadIdx.x;
  int tok = tid & 63, q = tid >> 6;
  int qu = __builtin_amdgcn_readfirstlane(q);   // wave-uniform quarter -> s_loads

  for (int c = 0; c < 4; ++c) {
    if (tid < NEXP) { s_cnt[tid] = 0; s_ps[tid] = 0.f; }
    int tb = (blockIdx.x << 8) + (c << 6);
    __syncthreads();  // xs free (prev chunk done) + hist reset visible

    // stage 64 rows: coalesced float4 read, swizzled scalar LDS writes, xb write
#pragma unroll
    for (int i = 0; i < 16; ++i) {
      int idx = i * 256 + tid;
      int row = idx >> 6, c4 = (idx & 63) << 2;
      float4 v = *(const float4*)(x + (size_t)(tb + row) * 256 + c4);
      int sw = row & 31;
      float* xr = xs + row * 256;
      xr[(c4 + 0) ^ sw] = v.x;
      xr[(c4 + 1) ^ sw] = v.y;
      xr[(c4 + 2) ^ sw] = v.z;
      xr[(c4 + 3) ^ sw] = v.w;
      ushort4 u4;
      u4.x = f2bf(v.x); u4.y = f2bf(v.y); u4.z = f2bf(v.z); u4.w = f2bf(v.w);
      *(ushort4*)(xb + (size_t)(tb + row) * 256 + c4) = u4;
    }
    __syncthreads();

    // per-thread fp64 partials over this thread's 64-d quarter
    double acc[8] = {0, 0, 0, 0, 0, 0, 0, 0};
    {
      int sw = tok & 31;
      const float* xr = xs + tok * 256;
#pragma unroll 4
      for (int d0 = 0; d0 < 64; ++d0) {
        int d = (qu << 6) + d0;
        double xv = (double)xr[d ^ sw];
#pragma unroll
        for (int e = 0; e < 8; ++e) acc[e] += xv * gd[e * 256 + d];
      }
    }

    // combine quarters: two 4-expert passes through red
    double l[8];
#pragma unroll
    for (int j = 0; j < 4; ++j) red[tid * 4 + j] = acc[j];
    __syncthreads();
    if (tid < 64) {
#pragma unroll
      for (int j = 0; j < 4; ++j)
        l[j] = red[tid * 4 + j] + red[(64 + tid) * 4 + j] +
               red[(128 + tid) * 4 + j] + red[(192 + tid) * 4 + j];
    }
    __syncthreads();
#pragma unroll
    for (int j = 0; j < 4; ++j) red[tid * 4 + j] = acc[4 + j];
    __syncthreads();
    if (tid < 64) {
#pragma unroll
      for (int j = 0; j < 4; ++j)
        l[4 + j] = red[tid * 4 + j] + red[(64 + tid) * 4 + j] +
                   red[(128 + tid) * 4 + j] + red[(192 + tid) * 4 + j];
      int t = tb + tid;
      // selection on exact fp64 logits (logic verbatim from shuffle version)
      int i1 = 0;
#pragma unroll
      for (int e = 1; e < NEXP; ++e) if (l[e] > l[i1]) i1 = e;
      int i2 = (i1 == 0) ? 1 : 0;
#pragma unroll
      for (int e = 0; e < NEXP; ++e) if (e != i1 && l[e] > l[i2]) i2 = e;
      double m = l[0];
#pragma unroll
      for (int e = 1; e < NEXP; ++e) m = (l[e] > m) ? l[e] : m;
      float pe[NEXP]; float s = 0.f;
#pragma unroll
      for (int e = 0; e < NEXP; ++e) { pe[e] = __expf((float)(l[e] - m)); s += pe[e]; }
      float inv = 1.f / s;
      float p1 = pe[i1] * inv, p2 = pe[i2] * inv;
      float wn = 1.f / (p1 + p2);
      pack[t] = i1 | (i2 << 8);
      tkw[t] = make_float2(p1 * wn, p2 * wn);
      atomicAdd(&s_cnt[i1], 1); atomicAdd(&s_cnt[i2], 1);
#pragma unroll
      for (int e = 0; e < NEXP; ++e) atomicAdd(&s_ps[e], pe[e] * inv);
    }
    __syncthreads();
    if (tid < NEXP) {
      part_cnt[(blockIdx.x * 4 + c) * NEXP + tid] = s_cnt[tid];
      part_psum[(blockIdx.x * 4 + c) * NEXP + tid] = s_ps[tid];
    }
  }
}

// ---------------- scan: offsets, totals, 256-PADDED expert bases, aux loss ----------------
__global__ __launch_bounds__(512) void k_scan(
    const int* __restrict__ part_cnt, const float* __restrict__ part_psum,
    int* __restrict__ block_off, int* __restrict__ cnt_total, float* __restrict__ out) {
  __shared__ float s_ps[NEXP];
  __shared__ int s_ct[NEXP];
  int lane = threadIdx.x & 63, wv = threadIdx.x >> 6;
  int base = lane * 32;
  int lsum = 0; float ps = 0.f;
#pragma unroll 8
  for (int j = 0; j < 32; ++j) {
    lsum += part_cnt[(base + j) * NEXP + wv];
    ps += part_psum[(base + j) * NEXP + wv];
  }
  int incl = lsum;
#pragma unroll
  for (int d = 1; d < 64; d <<= 1) { int t = __shfl_up(incl, d); if (lane >= d) incl += t; }
  int run = incl - lsum;
#pragma unroll 8
  for (int j = 0; j < 32; ++j) {
    int v = part_cnt[(base + j) * NEXP + wv];
    block_off[(base + j) * NEXP + wv] = run;
    run += v;
  }
#pragma unroll
  for (int d = 32; d; d >>= 1) ps += __shfl_xor(ps, d);
  int total = __shfl(incl, 63);
  if (lane == 0) { cnt_total[wv] = total; s_ct[wv] = total; s_ps[wv] = ps; }
  __syncthreads();
  if (threadIdx.x == 0) {
    double aux = 0.0; int rb = 0;
    for (int e = 0; e < NEXP; ++e) {
      aux += ((double)s_ct[e] / 131072.0) * ((double)s_ps[e] / 131072.0);
      cnt_total[8 + e] = rb;
      rb += (s_ct[e] + 255) & ~255;   // 256-aligned padded base
    }
    out[33554432] = (float)(8.0 * aux);
  }
}

// ---------------- scatter: per-expert lists + inverse map (over tkw) ----------------
__global__ void k_scatter(const int* __restrict__ pack, float2* tkw,
                          const int* __restrict__ block_off, const int* __restrict__ cnt_total,
                          int* __restrict__ tok_list, float* __restrict__ wt_list) {
  __shared__ int s_loc[NEXP];
  int tid = threadIdx.x;
  if (tid < NEXP) s_loc[tid] = 0;
  __syncthreads();
  int t = (blockIdx.x << 6) + tid;
  int p = pack[t];
  float2 wv = tkw[t];
  int e1 = p & 255, e2 = (p >> 8) & 255;
  int o1 = block_off[blockIdx.x * NEXP + e1];
  int p1 = atomicAdd(&s_loc[e1], 1);
  int i1 = cnt_total[8 + e1] + o1 + p1;
  tok_list[i1] = t; wt_list[i1] = wv.x;
  int o2 = block_off[blockIdx.x * NEXP + e2];
  int p2 = atomicAdd(&s_loc[e2], 1);
  int i2 = cnt_total[8 + e2] + o2 + p2;
  tok_list[i2] = t; wt_list[i2] = wv.y;
  tkw[t] = make_float2(__int_as_float(i1), __int_as_float(i2));
}

// ---------------- grouped GEMM1 + silu -> Hp panels (VALU-lean) ----------------
__global__ __launch_bounds__(512, 2) void k_gemm1(
    const unsigned short* __restrict__ xb, const unsigned short* __restrict__ P1,
    const float* __restrict__ b1, const int* __restrict__ tok_list,
    const int* __restrict__ cnt_total, unsigned short* __restrict__ Hp) {
  __shared__ __align__(16) unsigned short buf[65536];
  __shared__ int s_tok[128];

  int bid = (blockIdx.x & 7) * 514 + (blockIdx.x >> 3);  // grid 4112 = 8*514
  int e = -1, loc = 0, cum = 0, cnte = 0;
#pragma unroll
  for (int ee = 0; ee < NEXP; ++ee) {
    int ct = cnt_total[ee];
    int nb = ((ct + 127) >> 7) * 2;
    if (e < 0 && bid < cum + nb) { e = ee; loc = bid - cum; cnte = ct; }
    cum += nb;
  }
  if (e < 0) return;
  int mi = loc >> 1, ni = loc & 1;
  int nv = cnte - (mi << 7); if (nv > 128) nv = 128;
  int hbp = cnt_total[8 + e];

  int tid = threadIdx.x;
  int lane = tid & 63, w = tid >> 6, l15 = lane & 15, lg = lane >> 4;
  int wr = w >> 2, wc = w & 3;

  float b1v[4];
#pragma unroll
  for (int nt = 0; nt < 4; ++nt)
    b1v[nt] = b1[e * DHID + ni * 256 + wc * 64 + nt * 16 + l15];

  if (tid < 128) s_tok[tid] = tok_list[hbp + (mi << 7) + (tid < nv ? tid : nv - 1)];
  __syncthreads();

  int ar0 = tid >> 5;
  int ac = tid & 31;
#pragma unroll
  for (int i = 0; i < 8; ++i) {
    int row = i * 16 + ar0;
    gload16(xb + (size_t)s_tok[row] * DMODEL + (size_t)((ac ^ (row & 7)) << 3),
            &buf[(size_t)(i * 512 + w * 64) * 8]);
  }
  auto stage_b = [&](int kc) {
    const unsigned short* src = P1 + ((size_t)(e * 4 + kc) * 512 + ni * 256) * 64;
    int d = 32768 + (kc & 1) * 16384;
#pragma unroll
    for (int i = 0; i < 4; ++i) {
      int cidx = i * 512 + tid;
      gload16(src + (size_t)cidx * 8, &buf[d + (i * 512 + w * 64) * 8]);
    }
  };
  stage_b(0);
  asm volatile("s_waitcnt vmcnt(0)" ::: "memory");
  __builtin_amdgcn_s_barrier();
  __builtin_amdgcn_sched_barrier(0);

  int aidx[4][2], bidx[4][2];
#pragma unroll
  for (int mt = 0; mt < 4; ++mt) {
    int r = wr * 64 + mt * 16 + l15, r7 = r & 7;
#pragma unroll
    for (int ks = 0; ks < 2; ++ks) aidx[mt][ks] = r * 256 + (((ks * 4 + lg) ^ r7) << 3);
  }
#pragma unroll
  for (int nt = 0; nt < 4; ++nt) {
    int r = wc * 64 + nt * 16 + l15, r7 = r & 7;
#pragma unroll
    for (int ks = 0; ks < 2; ++ks) bidx[nt][ks] = r * 64 + (((ks * 4 + lg) ^ r7) << 3);
  }

  f32x4 acc[4][4];
#pragma unroll
  for (int mt = 0; mt < 4; ++mt)
#pragma unroll
    for (int nt = 0; nt < 4; ++nt) acc[mt][nt] = (f32x4){0.f, 0.f, 0.f, 0.f};

  for (int s = 0; s < 4; ++s) {
    if (s < 3) stage_b(s + 1);
    int abase = s * 64;
    int bbase = 32768 + (s & 1) * 16384;
#pragma unroll
    for (int ks = 0; ks < 2; ++ks) {
      short8 a[4], b[4];
#pragma unroll
      for (int mt = 0; mt < 4; ++mt) a[mt] = *(const short8*)&buf[abase + aidx[mt][ks]];
#pragma unroll
      for (int nt = 0; nt < 4; ++nt) b[nt] = *(const short8*)&buf[bbase + bidx[nt][ks]];
#pragma unroll
      for (int mt = 0; mt < 4; ++mt)
#pragma unroll
        for (int nt = 0; nt < 4; ++nt)
          acc[mt][nt] = __builtin_amdgcn_mfma_f32_16x16x32_bf16(a[mt], b[nt], acc[mt][nt], 0, 0, 0);
    }
    asm volatile("s_waitcnt vmcnt(0)" ::: "memory");
    __builtin_amdgcn_s_barrier();
    __builtin_amdgcn_sched_barrier(0);
  }

  // epilogue: fast silu (v_rcp), truncation bf16; XOR uses (lg*4+rr)&7
#pragma unroll
  for (int mt = 0; mt < 4; ++mt) {
    int rbase0 = (wr * 64 + mt * 16) * 256;
#pragma unroll
    for (int nt = 0; nt < 4; ++nt) {
      int col = wc * 64 + nt * 16 + l15;
      int c3 = col >> 3, c7 = col & 7;
#pragma unroll
      for (int rr = 0; rr < 4; ++rr) {
        int lr = lg * 4 + rr;
        int r7 = lr & 7;
        float z = acc[mt][nt][rr] + b1v[nt];
        float sv = z * __builtin_amdgcn_rcpf(1.f + __expf(-z));
        buf[rbase0 + lr * 256 + ((c3 ^ r7) << 3) + c7] =
            (unsigned short)(__float_as_uint(sv) >> 16);
      }
    }
  }
  __syncthreads();
  int blk = (hbp >> 8) + (mi >> 1);
  int rbase = (mi & 1) * 128;
  {
    int s32 = tid & 31;
    int c32 = s32 ^ (ar0 & 7);
    int kc = ni * 4 + (c32 >> 3), cs = c32 & 7;
    size_t gb = (((size_t)(blk * 8 + kc) * 256 + rbase + ar0) * 8 + (size_t)(cs ^ (ar0 & 7))) * 8;
    int lb = ar0 * 256 + s32 * 8;
    short8 z8 = {0, 0, 0, 0, 0, 0, 0, 0};
#pragma unroll
    for (int i = 0; i < 8; ++i) {
      int row = i * 16 + ar0;
      short8 v = (row < nv) ? *(const short8*)&buf[lb + i * 4096] : z8;
      *(short8*)&Hp[gb + (size_t)i * 1024] = v;
    }
  }
}

// ---------------- GEMM2 compute: K-loop w/ precomputed indices, trunc epilogue ----------
__global__ __launch_bounds__(512, 2) void k_gemm2c(
    unsigned short* Hp, const unsigned short* __restrict__ P2,
    const float* __restrict__ b2, const float* __restrict__ wt_list,
    const int* __restrict__ cnt_total) {
  __shared__ __align__(16) unsigned short buf[65536];
  __shared__ float s_wt[256];

  int bid = (blockIdx.x & 7) * 129 + (blockIdx.x >> 3);  // grid 1032 = 8*129
  int e = -1, mi = 0, cum = 0, cnte = 0;
#pragma unroll
  for (int ee = 0; ee < NEXP; ++ee) {
    int ct = cnt_total[ee];
    int nb = (ct + 255) >> 8;
    if (e < 0 && bid < cum + nb) { e = ee; mi = bid - cum; cnte = ct; }
    cum += nb;
  }
  if (e < 0) return;
  int nv = cnte - (mi << 8); if (nv > 256) nv = 256;
  int hbp = cnt_total[8 + e];
  int blk = (hbp >> 8) + mi;

  int tid = threadIdx.x;
  int lane = tid & 63, w = tid >> 6, l15 = lane & 15, lg = lane >> 4;
  int wr = w >> 2, wc = w & 3;

  float b2v[4];
#pragma unroll
  for (int nt = 0; nt < 4; ++nt)
    b2v[nt] = b2[e * DMODEL + wc * 64 + nt * 16 + l15];

  if (tid < 256) s_wt[tid] = (tid < nv) ? wt_list[hbp + (mi << 8) + tid] : 0.f;
  __syncthreads();

  auto stage = [&](int s) {
    int d = (s & 1) * 32768;
    const unsigned short* sa = Hp + (size_t)(blk * 8 + s) * 16384;
    const unsigned short* sb = P2 + (size_t)(e * 8 + s) * 16384;
#pragma unroll
    for (int i = 0; i < 4; ++i) {
      int c = i * 512 + tid;
      gload16(sa + (size_t)c * 8, &buf[d + (i * 512 + w * 64) * 8]);
    }
#pragma unroll
    for (int i = 0; i < 4; ++i) {
      int c = i * 512 + tid;
      gload16(sb + (size_t)c * 8, &buf[d + 16384 + (i * 512 + w * 64) * 8]);
    }
  };

  int aidx[8][2], bidx[4][2];
#pragma unroll
  for (int mt = 0; mt < 8; ++mt) {
    int r = wr * 128 + mt * 16 + l15, r7 = r & 7;
#pragma unroll
    for (int ks = 0; ks < 2; ++ks) aidx[mt][ks] = r * 64 + (((ks * 4 + lg) ^ r7) << 3);
  }
#pragma unroll
  for (int nt = 0; nt < 4; ++nt) {
    int r = wc * 64 + nt * 16 + l15, r7 = r & 7;
#pragma unroll
    for (int ks = 0; ks < 2; ++ks) bidx[nt][ks] = r * 64 + (((ks * 4 + lg) ^ r7) << 3);
  }

  f32x4 acc[8][4];
#pragma unroll
  for (int mt = 0; mt < 8; ++mt)
#pragma unroll
    for (int nt = 0; nt < 4; ++nt) acc[mt][nt] = (f32x4){0.f, 0.f, 0.f, 0.f};

  stage(0);
  asm volatile("s_waitcnt vmcnt(0)" ::: "memory");
  __builtin_amdgcn_s_barrier();
  __builtin_amdgcn_sched_barrier(0);

  for (int s = 0; s < 8; ++s) {
    if (s < 7) stage(s + 1);
    int ab = (s & 1) * 32768, bb = ab + 16384;
#pragma unroll
    for (int ks = 0; ks < 2; ++ks) {
      short8 a[8], b[4];
#pragma unroll
      for (int mt = 0; mt < 8; ++mt) a[mt] = *(const short8*)&buf[ab + aidx[mt][ks]];
#pragma unroll
      for (int nt = 0; nt < 4; ++nt) b[nt] = *(const short8*)&buf[bb + bidx[nt][ks]];
#pragma unroll
      for (int mt = 0; mt < 8; ++mt)
#pragma unroll
        for (int nt = 0; nt < 4; ++nt)
          acc[mt][nt] = __builtin_amdgcn_mfma_f32_16x16x32_bf16(a[mt], b[nt], acc[mt][nt], 0, 0, 0);
    }
    asm volatile("s_waitcnt vmcnt(0)" ::: "memory");
    __builtin_amdgcn_s_barrier();
    __builtin_amdgcn_sched_barrier(0);
  }

#pragma unroll
  for (int mt = 0; mt < 8; ++mt) {
    int rbase0 = (wr * 128 + mt * 16) * 256;
#pragma unroll
    for (int nt = 0; nt < 4; ++nt) {
      int col = wc * 64 + nt * 16 + l15;
#pragma unroll
      for (int rr = 0; rr < 4; ++rr) {
        int row = wr * 128 + mt * 16 + lg * 4 + rr;
        float v = s_wt[row] * (acc[mt][nt][rr] + b2v[nt]);
        buf[rbase0 + (lg * 4 + rr) * 256 + col] =
            (unsigned short)(__float_as_uint(v) >> 16);
      }
    }
  }
  __syncthreads();
  unsigned short* ydst = Hp + (size_t)blk * 131072;
#pragma unroll
  for (int i = 0; i < 16; ++i) {
    size_t cidx = (size_t)(i * 512 + tid) * 8;
    *(short8*)&ydst[cidx] = *(const short8*)&buf[cidx];
  }
}

// ---------------- reduce: out[t] = Y[s1] + Y[s2] ----------------
__global__ __launch_bounds__(256) void k_reduce(
    const unsigned short* __restrict__ Y, const float2* __restrict__ inv,
    float* __restrict__ out) {
  int g = blockIdx.x * 256 + threadIdx.x;
#pragma unroll
  for (int it = 0; it < 8; ++it) {
    int t = g >> 5;
    int cw = (g & 31) << 3;
    float2 iv = inv[t];
    int s1 = __float_as_int(iv.x), s2 = __float_as_int(iv.y);
    const unsigned short* y1 = Y + (size_t)(s1 >> 8) * 131072 + (size_t)(s1 & 255) * 256 + cw;
    const unsigned short* y2 = Y + (size_t)(s2 >> 8) * 131072 + (size_t)(s2 & 255) * 256 + cw;
    short8 a = *(const short8*)y1;
    short8 b = *(const short8*)y2;
    float* op = out + (size_t)t * 256 + cw;
    float4 r0, r1;
    r0.x = bf2f((unsigned short)a[0]) + bf2f((unsigned short)b[0]);
    r0.y = bf2f((unsigned short)a[1]) + bf2f((unsigned short)b[1]);
    r0.z = bf2f((unsigned short)a[2]) + bf2f((unsigned short)b[2]);
    r0.w = bf2f((unsigned short)a[3]) + bf2f((unsigned short)b[3]);
    r1.x = bf2f((unsigned short)a[4]) + bf2f((unsigned short)b[4]);
    r1.y = bf2f((unsigned short)a[5]) + bf2f((unsigned short)b[5]);
    r1.z = bf2f((unsigned short)a[6]) + bf2f((unsigned short)b[6]);
    r1.w = bf2f((unsigned short)a[7]) + bf2f((unsigned short)b[7]);
    *(float4*)op = r0;
    *(float4*)(op + 4) = r1;
    g += 2048 * 256;
  }
}

extern "C" void kernel_launch(void* const* d_in, const int* in_sizes, int n_in,
                              void* d_out, int out_size, void* d_ws, size_t ws_size,
                              hipStream_t stream) {
  const float* x    = (const float*)d_in[0];
  const float* gate = (const float*)d_in[1];
  const float* w1   = (const float*)d_in[2];
  const float* b1   = (const float*)d_in[3];
  const float* w2   = (const float*)d_in[4];
  const float* b2   = (const float*)d_in[5];
  float* out = (float*)d_out;
  char* ws = (char*)d_ws;

  unsigned short* xb  = (unsigned short*)(ws);
  unsigned short* P1  = (unsigned short*)(ws + 67108864);
  unsigned short* P2  = (unsigned short*)(ws + 69206016);
  int*    tok_list  = (int*)(ws + 71303168);
  float*  wt_list   = (float*)(ws + 72368128);
  int*    pack      = (int*)(ws + 73433088);
  float2* tkw       = (float2*)(ws + 73957376);
  int*    part_cnt  = (int*)(ws + 75005952);
  float*  part_psum = (float*)(ws + 75071488);
  int*    block_off = (int*)(ws + 75137024);
  int*    cnt_total = (int*)(ws + 75202560);
  double* gate_d    = (double*)(ws + 75235328);
  unsigned short* Hp = (unsigned short*)(ws + 75497472);

  k_wconv<<<512, 256, 0, stream>>>(w1, w2, gate, P1, P2, gate_d);
  k_router<<<512, 256, 0, stream>>>(x, gate_d, xb, pack, tkw, part_cnt, part_psum);
  k_scan<<<1, 512, 0, stream>>>(part_cnt, part_psum, block_off, cnt_total, out);
  k_scatter<<<2048, 64, 0, stream>>>(pack, tkw, block_off, cnt_total, tok_list, wt_list);
  k_gemm1<<<4112, 512, 0, stream>>>(xb, P1, b1, tok_list, cnt_total, Hp);
  k_gemm2c<<<1032, 512, 0, stream>>>(Hp, P2, b2, wt_list, cnt_total);
  k_reduce<<<2048, 256, 0, stream>>>(Hp, tkw, out);
}